// Round 1
// baseline (2722.374 us; speedup 1.0000x reference)
//
#include <hip/hip_runtime.h>
#include <cstddef>

#define SQLEN 2048
#define DMODEL 2048
#define NHEADS 16
#define DHEAD 128

// ---------------- GEMM: C[M,N] = A[M,K] @ B[N,K]^T  (row-major, fp32) -------
__global__ __launch_bounds__(256) void gemm_nt(const float* __restrict__ A,
                                               const float* __restrict__ B,
                                               float* __restrict__ C,
                                               int M, int N, int K) {
  __shared__ float As[128][17];
  __shared__ float Bs[128][17];
  int tid = threadIdx.x;
  int tx = tid & 15, ty = tid >> 4;
  int row0 = blockIdx.y * 128, col0 = blockIdx.x * 128;
  int lr = tid >> 2;            // 0..63
  int kq = (tid & 3) * 4;       // 0,4,8,12
  float acc[8][8];
#pragma unroll
  for (int i = 0; i < 8; i++)
#pragma unroll
    for (int j = 0; j < 8; j++) acc[i][j] = 0.f;

  for (int k0 = 0; k0 < K; k0 += 16) {
    float4 a0 = *(const float4*)(A + (size_t)(row0 + lr) * K + k0 + kq);
    float4 a1 = *(const float4*)(A + (size_t)(row0 + lr + 64) * K + k0 + kq);
    float4 b0 = *(const float4*)(B + (size_t)(col0 + lr) * K + k0 + kq);
    float4 b1 = *(const float4*)(B + (size_t)(col0 + lr + 64) * K + k0 + kq);
    As[lr][kq + 0] = a0.x; As[lr][kq + 1] = a0.y; As[lr][kq + 2] = a0.z; As[lr][kq + 3] = a0.w;
    As[lr + 64][kq + 0] = a1.x; As[lr + 64][kq + 1] = a1.y; As[lr + 64][kq + 2] = a1.z; As[lr + 64][kq + 3] = a1.w;
    Bs[lr][kq + 0] = b0.x; Bs[lr][kq + 1] = b0.y; Bs[lr][kq + 2] = b0.z; Bs[lr][kq + 3] = b0.w;
    Bs[lr + 64][kq + 0] = b1.x; Bs[lr + 64][kq + 1] = b1.y; Bs[lr + 64][kq + 2] = b1.z; Bs[lr + 64][kq + 3] = b1.w;
    __syncthreads();
#pragma unroll
    for (int kk = 0; kk < 16; kk++) {
      float ar[8], br[8];
#pragma unroll
      for (int i = 0; i < 8; i++) ar[i] = As[ty * 8 + i][kk];
#pragma unroll
      for (int j = 0; j < 8; j++) br[j] = Bs[tx * 8 + j][kk];
#pragma unroll
      for (int i = 0; i < 8; i++)
#pragma unroll
        for (int j = 0; j < 8; j++) acc[i][j] += ar[i] * br[j];
    }
    __syncthreads();
  }
#pragma unroll
  for (int i = 0; i < 8; i++) {
    float* crow = C + (size_t)(row0 + ty * 8 + i) * N + col0 + tx * 8;
    float4 c0 = {acc[i][0], acc[i][1], acc[i][2], acc[i][3]};
    float4 c1 = {acc[i][4], acc[i][5], acc[i][6], acc[i][7]};
    *(float4*)(crow) = c0;
    *(float4*)(crow + 4) = c1;
  }
}

// ---------------- alpha: a_raw[h,t] = base[h]*8*sigmoid(x[t]·W_alpha[h]+b) --
__global__ __launch_bounds__(256) void alpha_kernel(const float* __restrict__ x,
                                                    const float* __restrict__ W_alpha,
                                                    const float* __restrict__ b_alpha,
                                                    const float* __restrict__ alpha_base,
                                                    float* __restrict__ a_raw) {
  int gw = blockIdx.x * 4 + (threadIdx.x >> 6);  // (h,t) pair id
  int lane = threadIdx.x & 63;
  int h = gw >> 11;
  int t = gw & 2047;
  const float4* xr = (const float4*)(x + (size_t)t * DMODEL);
  const float4* wr = (const float4*)(W_alpha + (size_t)h * DMODEL);
  float s = 0.f;
  for (int i = lane; i < DMODEL / 4; i += 64) {
    float4 a = xr[i], b = wr[i];
    s += a.x * b.x + a.y * b.y + a.z * b.z + a.w * b.w;
  }
#pragma unroll
  for (int off = 32; off > 0; off >>= 1) s += __shfl_down(s, off);
  if (lane == 0) {
    float sig = 1.f / (1.f + expf(-(s + b_alpha[h])));
    a_raw[(size_t)h * SQLEN + t] = alpha_base[h] * 8.f * sig;
  }
}

// ---------------- cumsum over t per head ------------------------------------
__global__ __launch_bounds__(256) void cumsum_kernel(const float* __restrict__ a_raw,
                                                     float* __restrict__ A) {
  int h = blockIdx.x;
  __shared__ float part[256];
  int tid = threadIdx.x;
  float v[8];
  float s = 0.f;
#pragma unroll
  for (int i = 0; i < 8; i++) {
    v[i] = a_raw[(size_t)h * SQLEN + tid * 8 + i];
    s += v[i];
  }
  part[tid] = s;
  __syncthreads();
  for (int off = 1; off < 256; off <<= 1) {
    float tmp = (tid >= off) ? part[tid - off] : 0.f;
    __syncthreads();
    part[tid] += tmp;
    __syncthreads();
  }
  float run = (tid > 0) ? part[tid - 1] : 0.f;
#pragma unroll
  for (int i = 0; i < 8; i++) {
    run += v[i];
    A[(size_t)h * SQLEN + tid * 8 + i] = run;
  }
}

// ---------------- xPos + k decay scale + layout (h,t,d) ---------------------
__global__ __launch_bounds__(256) void xpos_kernel(const float* __restrict__ qkv,
                                                   const float* __restrict__ a_raw,
                                                   const int* __restrict__ offset_p,
                                                   float* __restrict__ q,
                                                   float* __restrict__ k,
                                                   float* __restrict__ v) {
  int idx = blockIdx.x * 256 + threadIdx.x;  // (h, t, j)  j in [0,64)
  int j = idx & 63;
  int t = (idx >> 6) & 2047;
  int h = idx >> 17;
  float pos = (float)(t + offset_p[0]);
  // freq = 10000^{-j/64} = 2^{-j*log2(10000)/64}
  float freq = exp2f(-(float)j * (13.287712379549449f / 64.f));
  float ang = pos * freq;
  float sn = sinf(ang), cs = cosf(ang);
  float zeta = (2.f * (float)j + 51.2f) / 179.2f;
  float lzp = log2f(zeta) * pos * (1.f / 512.f);
  float sc = exp2f(lzp);          // q scale
  float sci = exp2f(-lzp);        // k scale (inv)
  const float* row = qkv + (size_t)t * (3 * DMODEL);
  int base = h * DHEAD + j;
  float q1 = row[base], q2 = row[base + 64];
  float k1 = row[DMODEL + base], k2 = row[DMODEL + base + 64];
  float v1 = row[2 * DMODEL + base], v2 = row[2 * DMODEL + base + 64];
  size_t o = ((size_t)h * SQLEN + t) * DHEAD + j;
  q[o] = (q1 * cs - q2 * sn) * sc;
  q[o + 64] = (q2 * cs + q1 * sn) * sc;
  float km = (1.f - expf(a_raw[(size_t)h * SQLEN + t])) * sci;
  k[o] = (k1 * cs - k2 * sn) * km;
  k[o + 64] = (k2 * cs + k1 * sn) * km;
  v[o] = v1;
  v[o + 64] = v2;
}

// ---------------- retention: flash-style causal decay attention -------------
__global__ __launch_bounds__(256) void retention_kernel(const float* __restrict__ q,
                                                        const float* __restrict__ k,
                                                        const float* __restrict__ v,
                                                        const float* __restrict__ A,
                                                        const float* __restrict__ state,
                                                        float* __restrict__ ret) {
  int h = blockIdx.y;
  int i0 = blockIdx.x * 64;
  __shared__ float qs[64][129];
  __shared__ float ks[64][129];
  __shared__ float vs[64][132];  // pad 132 keeps float4 row alignment
  __shared__ float Ss[64][65];
  __shared__ float Ai[64];
  __shared__ float Aj[64];
  int tid = threadIdx.x;
  int tx = tid & 15, ty = tid >> 4;   // S-phase 16x16 grid, 4x4 microtile
  int rg = tid >> 5, cg = tid & 31;   // ret-phase: 8 rows x 4 cols ownership

  const float* qh = q + ((size_t)h * SQLEN + i0) * DHEAD;
  for (int l = tid; l < 64 * 32; l += 256) {
    int r = l >> 5, c = (l & 31) << 2;
    float4 t4 = *(const float4*)(qh + r * DHEAD + c);
    qs[r][c] = t4.x; qs[r][c + 1] = t4.y; qs[r][c + 2] = t4.z; qs[r][c + 3] = t4.w;
  }
  if (tid < 64) Ai[tid] = A[(size_t)h * SQLEN + i0 + tid];
  float acc[8][4];
#pragma unroll
  for (int i = 0; i < 8; i++)
#pragma unroll
    for (int j = 0; j < 4; j++) acc[i][j] = 0.f;
  __syncthreads();

  for (int j0 = 0; j0 <= i0; j0 += 64) {
    const float* kh = k + ((size_t)h * SQLEN + j0) * DHEAD;
    const float* vh = v + ((size_t)h * SQLEN + j0) * DHEAD;
    for (int l = tid; l < 64 * 32; l += 256) {
      int r = l >> 5, c = (l & 31) << 2;
      float4 t4 = *(const float4*)(kh + r * DHEAD + c);
      ks[r][c] = t4.x; ks[r][c + 1] = t4.y; ks[r][c + 2] = t4.z; ks[r][c + 3] = t4.w;
      float4 u4 = *(const float4*)(vh + r * DHEAD + c);
      vs[r][c] = u4.x; vs[r][c + 1] = u4.y; vs[r][c + 2] = u4.z; vs[r][c + 3] = u4.w;
    }
    if (tid < 64) Aj[tid] = A[(size_t)h * SQLEN + j0 + tid];
    __syncthreads();

    float s4[4][4];
#pragma unroll
    for (int a = 0; a < 4; a++)
#pragma unroll
      for (int b = 0; b < 4; b++) s4[a][b] = 0.f;
    for (int d = 0; d < 128; d++) {
      float aq[4], bk[4];
#pragma unroll
      for (int a = 0; a < 4; a++) aq[a] = qs[ty * 4 + a][d];
#pragma unroll
      for (int b = 0; b < 4; b++) bk[b] = ks[tx * 4 + b][d];
#pragma unroll
      for (int a = 0; a < 4; a++)
#pragma unroll
        for (int b = 0; b < 4; b++) s4[a][b] += aq[a] * bk[b];
    }
#pragma unroll
    for (int a = 0; a < 4; a++) {
      int i = ty * 4 + a;
#pragma unroll
      for (int b = 0; b < 4; b++) {
        int j = tx * 4 + b;
        float w = ((j0 + j) <= (i0 + i)) ? __expf(Ai[i] - Aj[j]) : 0.f;
        Ss[i][j] = s4[a][b] * w;
      }
    }
    __syncthreads();

    for (int j = 0; j < 64; j++) {
      float4 vv = *(const float4*)(&vs[j][cg * 4]);
#pragma unroll
      for (int rr = 0; rr < 8; rr++) {
        float sv = Ss[rg * 8 + rr][j];
        acc[rr][0] += sv * vv.x;
        acc[rr][1] += sv * vv.y;
        acc[rr][2] += sv * vv.z;
        acc[rr][3] += sv * vv.w;
      }
    }
    __syncthreads();
  }

  // cross term with initial state: acc += exp(Ai) * (q @ state_h)
  const float* sh = state + (size_t)h * DHEAD * DHEAD;
  float e[8];
#pragma unroll
  for (int rr = 0; rr < 8; rr++) e[rr] = __expf(Ai[rg * 8 + rr]);
  for (int d = 0; d < 128; d++) {
    float4 sv = *(const float4*)(sh + (size_t)d * DHEAD + cg * 4);
#pragma unroll
    for (int rr = 0; rr < 8; rr++) {
      float qe = qs[rg * 8 + rr][d] * e[rr];
      acc[rr][0] += qe * sv.x;
      acc[rr][1] += qe * sv.y;
      acc[rr][2] += qe * sv.z;
      acc[rr][3] += qe * sv.w;
    }
  }
#pragma unroll
  for (int rr = 0; rr < 8; rr++) {
    int i = i0 + rg * 8 + rr;
    float* dst = ret + (size_t)i * DMODEL + h * DHEAD + cg * 4;
    float4 o = {acc[rr][0], acc[rr][1], acc[rr][2], acc[rr][3]};
    *(float4*)dst = o;
  }
}

// ---------------- new_state partials over j-chunks --------------------------
__global__ __launch_bounds__(256) void state_partial(const float* __restrict__ k,
                                                     const float* __restrict__ v,
                                                     const float* __restrict__ A,
                                                     float* __restrict__ P) {
  int h = blockIdx.y, c = blockIdx.x;
  int tid = threadIdx.x;
  __shared__ float kb[4][128];
  __shared__ float vb[4][128];
  float B = A[(size_t)h * SQLEN + SQLEN - 1];
  int d0 = (tid >> 4) << 3;
  int e0 = (tid & 15) << 3;
  float acc[8][8];
#pragma unroll
  for (int a = 0; a < 8; a++)
#pragma unroll
    for (int b = 0; b < 8; b++) acc[a][b] = 0.f;

  for (int j0 = c * 128; j0 < c * 128 + 128; j0 += 4) {
    for (int l = tid; l < 512; l += 256) {
      int jj = l >> 7, d = l & 127;
      int j = j0 + jj;
      float w = __expf(B - A[(size_t)h * SQLEN + j]);
      kb[jj][d] = k[((size_t)h * SQLEN + j) * DHEAD + d] * w;
      vb[jj][d] = v[((size_t)h * SQLEN + j) * DHEAD + d];
    }
    __syncthreads();
#pragma unroll
    for (int jj = 0; jj < 4; jj++) {
      float4 k0 = *(const float4*)(&kb[jj][d0]);
      float4 k1 = *(const float4*)(&kb[jj][d0 + 4]);
      float4 v0 = *(const float4*)(&vb[jj][e0]);
      float4 v1 = *(const float4*)(&vb[jj][e0 + 4]);
      float kr[8] = {k0.x, k0.y, k0.z, k0.w, k1.x, k1.y, k1.z, k1.w};
      float vr[8] = {v0.x, v0.y, v0.z, v0.w, v1.x, v1.y, v1.z, v1.w};
#pragma unroll
      for (int a = 0; a < 8; a++)
#pragma unroll
        for (int b = 0; b < 8; b++) acc[a][b] += kr[a] * vr[b];
    }
    __syncthreads();
  }
  float* Pp = P + (size_t)(h * 16 + c) * 16384;
#pragma unroll
  for (int a = 0; a < 8; a++) {
    float* prow = Pp + (size_t)(d0 + a) * 128 + e0;
    float4 o0 = {acc[a][0], acc[a][1], acc[a][2], acc[a][3]};
    float4 o1 = {acc[a][4], acc[a][5], acc[a][6], acc[a][7]};
    *(float4*)(prow) = o0;
    *(float4*)(prow + 4) = o1;
  }
}

__global__ __launch_bounds__(256) void state_combine(const float* __restrict__ P,
                                                     const float* __restrict__ state,
                                                     const float* __restrict__ A,
                                                     float* __restrict__ out_state) {
  int idx = blockIdx.x * 256 + threadIdx.x;  // < 16*128*128
  int h = idx >> 14;
  int de = idx & 16383;
  float B = A[(size_t)h * SQLEN + SQLEN - 1];
  float s = __expf(B) * state[idx];
#pragma unroll
  for (int c = 0; c < 16; c++) s += P[(size_t)(h * 16 + c) * 16384 + de];
  out_state[idx] = s;
}

// ---------------- group norm ------------------------------------------------
__global__ __launch_bounds__(256) void groupnorm_kernel(const float* __restrict__ ret,
                                                        const float* __restrict__ w,
                                                        const float* __restrict__ b,
                                                        float* __restrict__ out) {
  int gw = blockIdx.x * 4 + (threadIdx.x >> 6);
  int lane = threadIdx.x & 63;
  int t = gw >> 4, h = gw & 15;
  const float* p = ret + (size_t)t * DMODEL + h * DHEAD;
  float x0 = p[lane], x1 = p[lane + 64];
  float s = x0 + x1, ss = x0 * x0 + x1 * x1;
#pragma unroll
  for (int off = 32; off > 0; off >>= 1) {
    s += __shfl_xor(s, off);
    ss += __shfl_xor(ss, off);
  }
  float mu = s * (1.f / 128.f);
  float var = ss * (1.f / 128.f) - mu * mu;
  float inv = rsqrtf(var + 1e-5f);
  int cidx = h * DHEAD + lane;
  float* o = out + (size_t)t * DMODEL;
  o[cidx] = (x0 - mu) * inv * w[cidx] + b[cidx];
  o[cidx + 64] = (x1 - mu) * inv * w[cidx + 64] + b[cidx + 64];
}

// ---------------- swish(G) * ret_n ------------------------------------------
__global__ __launch_bounds__(256) void swishmul_kernel(const float* __restrict__ G,
                                                       const float* __restrict__ rn,
                                                       float* __restrict__ H) {
  int i = blockIdx.x * 256 + threadIdx.x;
  float4 g = ((const float4*)G)[i];
  float4 r = ((const float4*)rn)[i];
  float4 o;
  o.x = g.x / (1.f + expf(-g.x)) * r.x;
  o.y = g.y / (1.f + expf(-g.y)) * r.y;
  o.z = g.z / (1.f + expf(-g.z)) * r.z;
  o.w = g.w / (1.f + expf(-g.w)) * r.w;
  ((float4*)H)[i] = o;
}

extern "C" void kernel_launch(void* const* d_in, const int* in_sizes, int n_in,
                              void* d_out, int out_size, void* d_ws, size_t ws_size,
                              hipStream_t stream) {
  const float* x = (const float*)d_in[0];
  const float* state = (const float*)d_in[1];
  const float* W_qkv = (const float*)d_in[2];
  const float* W_alpha = (const float*)d_in[3];
  const float* b_alpha = (const float*)d_in[4];
  const float* alpha_base = (const float*)d_in[5];
  const float* gn_w = (const float*)d_in[6];
  const float* gn_b = (const float*)d_in[7];
  const float* W_out = (const float*)d_in[8];
  const float* W_gate = (const float*)d_in[9];
  const int* offset = (const int*)d_in[10];

  float* ws = (float*)d_ws;
  // layout (floats). qkv region (12.58M) is reused by G/H/P after xpos.
  float* qkv = ws;                    // 2048*6144
  float* G   = ws;                    // 2048*2048 (overlay, after qkv dead)
  float* H   = ws + 4194304;          // 2048*2048 (overlay)
  float* P   = ws + 8388608;          // 16*16*128*128 (overlay)
  float* q   = ws + 12582912;         // 16*2048*128
  float* k   = ws + 16777216;
  float* v   = ws + 20971520;
  float* ret = ws + 25165824;         // 2048*2048
  float* rn  = ws + 29360128;         // 2048*2048
  float* araw = ws + 33554432;        // 16*2048
  float* Acum = ws + 33587200;        // 16*2048

  float* out = (float*)d_out;
  float* out_state = out + 4194304;

  dim3 blk(256);
  gemm_nt<<<dim3(48, 16), blk, 0, stream>>>(x, W_qkv, qkv, 2048, 6144, 2048);
  alpha_kernel<<<dim3(8192), blk, 0, stream>>>(x, W_alpha, b_alpha, alpha_base, araw);
  cumsum_kernel<<<dim3(16), blk, 0, stream>>>(araw, Acum);
  xpos_kernel<<<dim3(8192), blk, 0, stream>>>(qkv, araw, offset, q, k, v);
  retention_kernel<<<dim3(32, 16), blk, 0, stream>>>(q, k, v, Acum, state, ret);
  state_partial<<<dim3(16, 16), blk, 0, stream>>>(k, v, Acum, P);
  state_combine<<<dim3(1024), blk, 0, stream>>>(P, state, Acum, out_state);
  groupnorm_kernel<<<dim3(8192), blk, 0, stream>>>(ret, gn_w, gn_b, rn);
  gemm_nt<<<dim3(16, 16), blk, 0, stream>>>(rn, W_gate, G, 2048, 2048, 2048);
  swishmul_kernel<<<dim3(4096), blk, 0, stream>>>(G, rn, H);
  gemm_nt<<<dim3(16, 16), blk, 0, stream>>>(H, W_out, out, 2048, 2048, 2048);
}

// Round 2
// 1298.502 us; speedup vs baseline: 2.0965x; 2.0965x over previous
//
#include <hip/hip_runtime.h>
#include <cstddef>

#define SQLEN 2048
#define DMODEL 2048
#define NHEADS 16
#define DHEAD 128

typedef __attribute__((ext_vector_type(8))) short bf16x8;
typedef __attribute__((ext_vector_type(4))) float floatx4;

__device__ __forceinline__ unsigned short f2bf(float f) {
  union { float f; unsigned u; } c; c.f = f;
  unsigned u = c.u;
  unsigned r = u + 0x7fffu + ((u >> 16) & 1u);
  return (unsigned short)(r >> 16);
}

// ---------------- fp32 -> bf16 convert (vectorized) -------------------------
__global__ __launch_bounds__(256) void f2b_kernel(const float4* __restrict__ in,
                                                  ushort4* __restrict__ out) {
  int i = blockIdx.x * 256 + threadIdx.x;
  float4 v = in[i];
  ushort4 o;
  o.x = f2bf(v.x); o.y = f2bf(v.y); o.z = f2bf(v.z); o.w = f2bf(v.w);
  out[i] = o;
}

// ---------------- bf16 MFMA GEMM: C[M,N] = A[M,K] @ B[N,K]^T ----------------
// m97 structure: 128x128 tile, BK=32, global_load_lds width-16 staging,
// 4 waves, each wave computes a 64x64 block as 4x4 grid of 16x16x32 MFMAs.
__global__ __launch_bounds__(256) void gemm_bf16_nt(const unsigned short* __restrict__ A,
                                                    const unsigned short* __restrict__ B,
                                                    float* __restrict__ C,
                                                    int M, int N, int K) {
  __shared__ __align__(16) unsigned short As[128 * 32];
  __shared__ __align__(16) unsigned short Bs[128 * 32];
  int tid = threadIdx.x;
  int wave = tid >> 6;
  int lane = tid & 63;
  int wm = wave >> 1, wn = wave & 1;
  int quad = lane >> 4, m16 = lane & 15;
  int row0 = blockIdx.y * 128, col0 = blockIdx.x * 128;

  floatx4 acc[4][4];
#pragma unroll
  for (int i = 0; i < 4; i++)
#pragma unroll
    for (int j = 0; j < 4; j++) acc[i][j] = (floatx4){0.f, 0.f, 0.f, 0.f};

  // staging chunk ids: chunk c = 16B = 8 bf16; 4 chunks per 64B row of the tile
  int c0 = tid, c1 = tid + 256;
  int r0c = c0 >> 2, q0c = (c0 & 3) * 8;
  int r1c = c1 >> 2, q1c = (c1 & 3) * 8;

  const size_t sK = (size_t)K;
  for (int k0 = 0; k0 < K; k0 += 32) {
    __builtin_amdgcn_global_load_lds(
        (const __attribute__((address_space(1))) unsigned int*)(A + (size_t)(row0 + r0c) * sK + k0 + q0c),
        (__attribute__((address_space(3))) unsigned int*)(As + c0 * 8), 16, 0, 0);
    __builtin_amdgcn_global_load_lds(
        (const __attribute__((address_space(1))) unsigned int*)(A + (size_t)(row0 + r1c) * sK + k0 + q1c),
        (__attribute__((address_space(3))) unsigned int*)(As + c1 * 8), 16, 0, 0);
    __builtin_amdgcn_global_load_lds(
        (const __attribute__((address_space(1))) unsigned int*)(B + (size_t)(col0 + r0c) * sK + k0 + q0c),
        (__attribute__((address_space(3))) unsigned int*)(Bs + c0 * 8), 16, 0, 0);
    __builtin_amdgcn_global_load_lds(
        (const __attribute__((address_space(1))) unsigned int*)(B + (size_t)(col0 + r1c) * sK + k0 + q1c),
        (__attribute__((address_space(3))) unsigned int*)(Bs + c1 * 8), 16, 0, 0);
    __syncthreads();

    bf16x8 af[4], bfr[4];
#pragma unroll
    for (int i = 0; i < 4; i++)
      af[i] = *(const bf16x8*)(As + (wm * 64 + i * 16 + m16) * 32 + quad * 8);
#pragma unroll
    for (int j = 0; j < 4; j++)
      bfr[j] = *(const bf16x8*)(Bs + (wn * 64 + j * 16 + m16) * 32 + quad * 8);
#pragma unroll
    for (int i = 0; i < 4; i++)
#pragma unroll
      for (int j = 0; j < 4; j++)
        acc[i][j] = __builtin_amdgcn_mfma_f32_16x16x32_bf16(af[i], bfr[j], acc[i][j], 0, 0, 0);
    __syncthreads();
  }

  // C/D layout: col = lane&15, row = quad*4 + reg  [m89/m91 verified]
#pragma unroll
  for (int i = 0; i < 4; i++) {
#pragma unroll
    for (int j = 0; j < 4; j++) {
      int rr = row0 + wm * 64 + i * 16 + quad * 4;
      int cc = col0 + wn * 64 + j * 16 + m16;
#pragma unroll
      for (int r = 0; r < 4; r++)
        C[(size_t)(rr + r) * N + cc] = acc[i][j][r];
    }
  }
}

// ---------------- alpha: a_raw[h,t] = base[h]*8*sigmoid(x[t]·W_alpha[h]+b) --
__global__ __launch_bounds__(256) void alpha_kernel(const float* __restrict__ x,
                                                    const float* __restrict__ W_alpha,
                                                    const float* __restrict__ b_alpha,
                                                    const float* __restrict__ alpha_base,
                                                    float* __restrict__ a_raw) {
  int gw = blockIdx.x * 4 + (threadIdx.x >> 6);  // (h,t) pair id
  int lane = threadIdx.x & 63;
  int h = gw >> 11;
  int t = gw & 2047;
  const float4* xr = (const float4*)(x + (size_t)t * DMODEL);
  const float4* wr = (const float4*)(W_alpha + (size_t)h * DMODEL);
  float s = 0.f;
  for (int i = lane; i < DMODEL / 4; i += 64) {
    float4 a = xr[i], b = wr[i];
    s += a.x * b.x + a.y * b.y + a.z * b.z + a.w * b.w;
  }
#pragma unroll
  for (int off = 32; off > 0; off >>= 1) s += __shfl_down(s, off);
  if (lane == 0) {
    float sig = 1.f / (1.f + expf(-(s + b_alpha[h])));
    a_raw[(size_t)h * SQLEN + t] = alpha_base[h] * 8.f * sig;
  }
}

// ---------------- cumsum over t per head ------------------------------------
__global__ __launch_bounds__(256) void cumsum_kernel(const float* __restrict__ a_raw,
                                                     float* __restrict__ A) {
  int h = blockIdx.x;
  __shared__ float part[256];
  int tid = threadIdx.x;
  float v[8];
  float s = 0.f;
#pragma unroll
  for (int i = 0; i < 8; i++) {
    v[i] = a_raw[(size_t)h * SQLEN + tid * 8 + i];
    s += v[i];
  }
  part[tid] = s;
  __syncthreads();
  for (int off = 1; off < 256; off <<= 1) {
    float tmp = (tid >= off) ? part[tid - off] : 0.f;
    __syncthreads();
    part[tid] += tmp;
    __syncthreads();
  }
  float run = (tid > 0) ? part[tid - 1] : 0.f;
#pragma unroll
  for (int i = 0; i < 8; i++) {
    run += v[i];
    A[(size_t)h * SQLEN + tid * 8 + i] = run;
  }
}

// ---------------- xPos + k decay scale + layout (h,t,d) ---------------------
__global__ __launch_bounds__(256) void xpos_kernel(const float* __restrict__ qkv,
                                                   const float* __restrict__ a_raw,
                                                   const int* __restrict__ offset_p,
                                                   float* __restrict__ q,
                                                   float* __restrict__ k,
                                                   float* __restrict__ v) {
  int idx = blockIdx.x * 256 + threadIdx.x;  // (h, t, j)  j in [0,64)
  int j = idx & 63;
  int t = (idx >> 6) & 2047;
  int h = idx >> 17;
  float pos = (float)(t + offset_p[0]);
  float freq = exp2f(-(float)j * (13.287712379549449f / 64.f));
  float ang = pos * freq;
  float sn = sinf(ang), cs = cosf(ang);
  float zeta = (2.f * (float)j + 51.2f) / 179.2f;
  float lzp = log2f(zeta) * pos * (1.f / 512.f);
  float sc = exp2f(lzp);          // q scale
  float sci = exp2f(-lzp);        // k scale (inv)
  const float* row = qkv + (size_t)t * (3 * DMODEL);
  int base = h * DHEAD + j;
  float q1 = row[base], q2 = row[base + 64];
  float k1 = row[DMODEL + base], k2 = row[DMODEL + base + 64];
  float v1 = row[2 * DMODEL + base], v2 = row[2 * DMODEL + base + 64];
  size_t o = ((size_t)h * SQLEN + t) * DHEAD + j;
  q[o] = (q1 * cs - q2 * sn) * sc;
  q[o + 64] = (q2 * cs + q1 * sn) * sc;
  float km = (1.f - expf(a_raw[(size_t)h * SQLEN + t])) * sci;
  k[o] = (k1 * cs - k2 * sn) * km;
  k[o + 64] = (k2 * cs + k1 * sn) * km;
  v[o] = v1;
  v[o + 64] = v2;
}

// ---------------- retention: flash-style causal decay attention -------------
__global__ __launch_bounds__(256) void retention_kernel(const float* __restrict__ q,
                                                        const float* __restrict__ k,
                                                        const float* __restrict__ v,
                                                        const float* __restrict__ A,
                                                        const float* __restrict__ state,
                                                        float* __restrict__ ret) {
  int h = blockIdx.y;
  int i0 = blockIdx.x * 64;
  __shared__ float qs[64][129];
  __shared__ float ks[64][129];
  __shared__ float vs[64][132];
  __shared__ float Ss[64][65];
  __shared__ float Ai[64];
  __shared__ float Aj[64];
  int tid = threadIdx.x;
  int tx = tid & 15, ty = tid >> 4;
  int rg = tid >> 5, cg = tid & 31;

  const float* qh = q + ((size_t)h * SQLEN + i0) * DHEAD;
  for (int l = tid; l < 64 * 32; l += 256) {
    int r = l >> 5, c = (l & 31) << 2;
    float4 t4 = *(const float4*)(qh + r * DHEAD + c);
    qs[r][c] = t4.x; qs[r][c + 1] = t4.y; qs[r][c + 2] = t4.z; qs[r][c + 3] = t4.w;
  }
  if (tid < 64) Ai[tid] = A[(size_t)h * SQLEN + i0 + tid];
  float acc[8][4];
#pragma unroll
  for (int i = 0; i < 8; i++)
#pragma unroll
    for (int j = 0; j < 4; j++) acc[i][j] = 0.f;
  __syncthreads();

  for (int j0 = 0; j0 <= i0; j0 += 64) {
    const float* kh = k + ((size_t)h * SQLEN + j0) * DHEAD;
    const float* vh = v + ((size_t)h * SQLEN + j0) * DHEAD;
    for (int l = tid; l < 64 * 32; l += 256) {
      int r = l >> 5, c = (l & 31) << 2;
      float4 t4 = *(const float4*)(kh + r * DHEAD + c);
      ks[r][c] = t4.x; ks[r][c + 1] = t4.y; ks[r][c + 2] = t4.z; ks[r][c + 3] = t4.w;
      float4 u4 = *(const float4*)(vh + r * DHEAD + c);
      vs[r][c] = u4.x; vs[r][c + 1] = u4.y; vs[r][c + 2] = u4.z; vs[r][c + 3] = u4.w;
    }
    if (tid < 64) Aj[tid] = A[(size_t)h * SQLEN + j0 + tid];
    __syncthreads();

    float s4[4][4];
#pragma unroll
    for (int a = 0; a < 4; a++)
#pragma unroll
      for (int b = 0; b < 4; b++) s4[a][b] = 0.f;
    for (int d = 0; d < 128; d++) {
      float aq[4], bk[4];
#pragma unroll
      for (int a = 0; a < 4; a++) aq[a] = qs[ty * 4 + a][d];
#pragma unroll
      for (int b = 0; b < 4; b++) bk[b] = ks[tx * 4 + b][d];
#pragma unroll
      for (int a = 0; a < 4; a++)
#pragma unroll
        for (int b = 0; b < 4; b++) s4[a][b] += aq[a] * bk[b];
    }
#pragma unroll
    for (int a = 0; a < 4; a++) {
      int i = ty * 4 + a;
#pragma unroll
      for (int b = 0; b < 4; b++) {
        int j = tx * 4 + b;
        float w = ((j0 + j) <= (i0 + i)) ? __expf(Ai[i] - Aj[j]) : 0.f;
        Ss[i][j] = s4[a][b] * w;
      }
    }
    __syncthreads();

    for (int j = 0; j < 64; j++) {
      float4 vv = *(const float4*)(&vs[j][cg * 4]);
#pragma unroll
      for (int rr = 0; rr < 8; rr++) {
        float sv = Ss[rg * 8 + rr][j];
        acc[rr][0] += sv * vv.x;
        acc[rr][1] += sv * vv.y;
        acc[rr][2] += sv * vv.z;
        acc[rr][3] += sv * vv.w;
      }
    }
    __syncthreads();
  }

  const float* sh = state + (size_t)h * DHEAD * DHEAD;
  float e[8];
#pragma unroll
  for (int rr = 0; rr < 8; rr++) e[rr] = __expf(Ai[rg * 8 + rr]);
  for (int d = 0; d < 128; d++) {
    float4 sv = *(const float4*)(sh + (size_t)d * DHEAD + cg * 4);
#pragma unroll
    for (int rr = 0; rr < 8; rr++) {
      float qe = qs[rg * 8 + rr][d] * e[rr];
      acc[rr][0] += qe * sv.x;
      acc[rr][1] += qe * sv.y;
      acc[rr][2] += qe * sv.z;
      acc[rr][3] += qe * sv.w;
    }
  }
#pragma unroll
  for (int rr = 0; rr < 8; rr++) {
    int i = i0 + rg * 8 + rr;
    float* dst = ret + (size_t)i * DMODEL + h * DHEAD + cg * 4;
    float4 o = {acc[rr][0], acc[rr][1], acc[rr][2], acc[rr][3]};
    *(float4*)dst = o;
  }
}

// ---------------- new_state partials over j-chunks --------------------------
__global__ __launch_bounds__(256) void state_partial(const float* __restrict__ k,
                                                     const float* __restrict__ v,
                                                     const float* __restrict__ A,
                                                     float* __restrict__ P) {
  int h = blockIdx.y, c = blockIdx.x;
  int tid = threadIdx.x;
  __shared__ float kb[4][128];
  __shared__ float vb[4][128];
  float B = A[(size_t)h * SQLEN + SQLEN - 1];
  int d0 = (tid >> 4) << 3;
  int e0 = (tid & 15) << 3;
  float acc[8][8];
#pragma unroll
  for (int a = 0; a < 8; a++)
#pragma unroll
    for (int b = 0; b < 8; b++) acc[a][b] = 0.f;

  for (int j0 = c * 128; j0 < c * 128 + 128; j0 += 4) {
    for (int l = tid; l < 512; l += 256) {
      int jj = l >> 7, d = l & 127;
      int j = j0 + jj;
      float w = __expf(B - A[(size_t)h * SQLEN + j]);
      kb[jj][d] = k[((size_t)h * SQLEN + j) * DHEAD + d] * w;
      vb[jj][d] = v[((size_t)h * SQLEN + j) * DHEAD + d];
    }
    __syncthreads();
#pragma unroll
    for (int jj = 0; jj < 4; jj++) {
      float4 k0 = *(const float4*)(&kb[jj][d0]);
      float4 k1 = *(const float4*)(&kb[jj][d0 + 4]);
      float4 v0 = *(const float4*)(&vb[jj][e0]);
      float4 v1 = *(const float4*)(&vb[jj][e0 + 4]);
      float kr[8] = {k0.x, k0.y, k0.z, k0.w, k1.x, k1.y, k1.z, k1.w};
      float vr[8] = {v0.x, v0.y, v0.z, v0.w, v1.x, v1.y, v1.z, v1.w};
#pragma unroll
      for (int a = 0; a < 8; a++)
#pragma unroll
        for (int b = 0; b < 8; b++) acc[a][b] += kr[a] * vr[b];
    }
    __syncthreads();
  }
  float* Pp = P + (size_t)(h * 16 + c) * 16384;
#pragma unroll
  for (int a = 0; a < 8; a++) {
    float* prow = Pp + (size_t)(d0 + a) * 128 + e0;
    float4 o0 = {acc[a][0], acc[a][1], acc[a][2], acc[a][3]};
    float4 o1 = {acc[a][4], acc[a][5], acc[a][6], acc[a][7]};
    *(float4*)(prow) = o0;
    *(float4*)(prow + 4) = o1;
  }
}

__global__ __launch_bounds__(256) void state_combine(const float* __restrict__ P,
                                                     const float* __restrict__ state,
                                                     const float* __restrict__ A,
                                                     float* __restrict__ out_state) {
  int idx = blockIdx.x * 256 + threadIdx.x;  // < 16*128*128
  int h = idx >> 14;
  int de = idx & 16383;
  float B = A[(size_t)h * SQLEN + SQLEN - 1];
  float s = __expf(B) * state[idx];
#pragma unroll
  for (int c = 0; c < 16; c++) s += P[(size_t)(h * 16 + c) * 16384 + de];
  out_state[idx] = s;
}

// ---------------- group norm ------------------------------------------------
__global__ __launch_bounds__(256) void groupnorm_kernel(const float* __restrict__ ret,
                                                        const float* __restrict__ w,
                                                        const float* __restrict__ b,
                                                        float* __restrict__ out) {
  int gw = blockIdx.x * 4 + (threadIdx.x >> 6);
  int lane = threadIdx.x & 63;
  int t = gw >> 4, h = gw & 15;
  const float* p = ret + (size_t)t * DMODEL + h * DHEAD;
  float x0 = p[lane], x1 = p[lane + 64];
  float s = x0 + x1, ss = x0 * x0 + x1 * x1;
#pragma unroll
  for (int off = 32; off > 0; off >>= 1) {
    s += __shfl_xor(s, off);
    ss += __shfl_xor(ss, off);
  }
  float mu = s * (1.f / 128.f);
  float var = ss * (1.f / 128.f) - mu * mu;
  float inv = rsqrtf(var + 1e-5f);
  int cidx = h * DHEAD + lane;
  float* o = out + (size_t)t * DMODEL;
  o[cidx] = (x0 - mu) * inv * w[cidx] + b[cidx];
  o[cidx + 64] = (x1 - mu) * inv * w[cidx + 64] + b[cidx + 64];
}

// ---------------- swish(G) * ret_n ------------------------------------------
__global__ __launch_bounds__(256) void swishmul_kernel(const float* __restrict__ G,
                                                       const float* __restrict__ rn,
                                                       float* __restrict__ H) {
  int i = blockIdx.x * 256 + threadIdx.x;
  float4 g = ((const float4*)G)[i];
  float4 r = ((const float4*)rn)[i];
  float4 o;
  o.x = g.x / (1.f + expf(-g.x)) * r.x;
  o.y = g.y / (1.f + expf(-g.y)) * r.y;
  o.z = g.z / (1.f + expf(-g.z)) * r.z;
  o.w = g.w / (1.f + expf(-g.w)) * r.w;
  ((float4*)H)[i] = o;
}

extern "C" void kernel_launch(void* const* d_in, const int* in_sizes, int n_in,
                              void* d_out, int out_size, void* d_ws, size_t ws_size,
                              hipStream_t stream) {
  const float* x = (const float*)d_in[0];
  const float* state = (const float*)d_in[1];
  const float* W_qkv = (const float*)d_in[2];
  const float* W_alpha = (const float*)d_in[3];
  const float* b_alpha = (const float*)d_in[4];
  const float* alpha_base = (const float*)d_in[5];
  const float* gn_w = (const float*)d_in[6];
  const float* gn_b = (const float*)d_in[7];
  const float* W_out = (const float*)d_in[8];
  const float* W_gate = (const float*)d_in[9];
  const int* offset = (const int*)d_in[10];

  float* ws = (float*)d_ws;
  // fp32 regions (floats):
  float* qkv = ws;                    // [0, 12.58M) alive gemm1 -> xpos
  float* G   = ws;                    // overlay on dead qkv
  float* H   = ws + 4194304;          // overlay
  float* P   = ws + 8388608;          // overlay
  float* q   = ws + 12582912;         // 16*2048*128
  float* k   = ws + 16777216;
  float* v   = ws + 20971520;
  float* ret = ws + 25165824;         // 2048*2048
  float* rn  = ws + 29360128;         // 2048*2048
  float* araw = ws + 33554432;        // 16*2048
  float* Acum = ws + 33587200;        // 16*2048

  // bf16 overlays (ushort):
  // phase 1 (pre-xpos): xb over q region, Wqkvb over k+v region
  unsigned short* xb    = (unsigned short*)(ws + 12582912);  // 4.19M bf16 = 2.1M fl
  unsigned short* Wqkvb = (unsigned short*)(ws + 16777216);  // 12.58M bf16 = 6.29M fl
  // phase 2 (post-state): rnb+Wgateb over q region, Woutb+Hb over k region
  unsigned short* rnb    = (unsigned short*)(ws + 12582912);
  unsigned short* Wgateb = (unsigned short*)(ws + 14680064);
  unsigned short* Woutb  = (unsigned short*)(ws + 16777216);
  unsigned short* Hb     = (unsigned short*)(ws + 18874368);

  float* out = (float*)d_out;
  float* out_state = out + 4194304;

  dim3 blk(256);
  // phase 1: qkv GEMM in bf16 MFMA
  f2b_kernel<<<dim3(4096), blk, 0, stream>>>((const float4*)x, (ushort4*)xb);
  f2b_kernel<<<dim3(12288), blk, 0, stream>>>((const float4*)W_qkv, (ushort4*)Wqkvb);
  gemm_bf16_nt<<<dim3(48, 16), blk, 0, stream>>>(xb, Wqkvb, qkv, 2048, 6144, 2048);

  alpha_kernel<<<dim3(8192), blk, 0, stream>>>(x, W_alpha, b_alpha, alpha_base, araw);
  cumsum_kernel<<<dim3(16), blk, 0, stream>>>(araw, Acum);
  xpos_kernel<<<dim3(8192), blk, 0, stream>>>(qkv, araw, offset, q, k, v);

  retention_kernel<<<dim3(32, 16), blk, 0, stream>>>(q, k, v, Acum, state, ret);
  state_partial<<<dim3(16, 16), blk, 0, stream>>>(k, v, Acum, P);
  state_combine<<<dim3(1024), blk, 0, stream>>>(P, state, Acum, out_state);
  groupnorm_kernel<<<dim3(8192), blk, 0, stream>>>(ret, gn_w, gn_b, rn);

  // phase 2: output GEMMs in bf16 MFMA (q/k/v dead now)
  f2b_kernel<<<dim3(4096), blk, 0, stream>>>((const float4*)rn, (ushort4*)rnb);
  f2b_kernel<<<dim3(4096), blk, 0, stream>>>((const float4*)W_gate, (ushort4*)Wgateb);
  f2b_kernel<<<dim3(4096), blk, 0, stream>>>((const float4*)W_out, (ushort4*)Woutb);
  gemm_bf16_nt<<<dim3(16, 16), blk, 0, stream>>>(rnb, Wgateb, G, 2048, 2048, 2048);
  swishmul_kernel<<<dim3(4096), blk, 0, stream>>>(G, rn, H);
  f2b_kernel<<<dim3(4096), blk, 0, stream>>>((const float4*)H, (ushort4*)Hb);
  gemm_bf16_nt<<<dim3(16, 16), blk, 0, stream>>>(Hb, Woutb, out, 2048, 2048, 2048);
}

// Round 3
// 528.061 us; speedup vs baseline: 5.1554x; 2.4590x over previous
//
#include <hip/hip_runtime.h>
#include <cstddef>

#define SQLEN 2048
#define DMODEL 2048
#define NHEADS 16
#define DHEAD 128

typedef __attribute__((ext_vector_type(8))) short bf16x8;
typedef __attribute__((ext_vector_type(4))) float floatx4;

__device__ __forceinline__ unsigned short f2bf(float f) {
  union { float f; unsigned u; } c; c.f = f;
  unsigned u = c.u;
  unsigned r = u + 0x7fffu + ((u >> 16) & 1u);
  return (unsigned short)(r >> 16);
}

// ---------------- fp32 -> bf16 convert (vectorized) -------------------------
__global__ __launch_bounds__(256) void f2b_kernel(const float4* __restrict__ in,
                                                  ushort4* __restrict__ out) {
  int i = blockIdx.x * 256 + threadIdx.x;
  float4 v = in[i];
  ushort4 o;
  o.x = f2bf(v.x); o.y = f2bf(v.y); o.z = f2bf(v.z); o.w = f2bf(v.w);
  out[i] = o;
}

// ---------------- bf16 MFMA GEMM: C[M,N] = A[M,K] @ B[N,K]^T ----------------
__global__ __launch_bounds__(256) void gemm_bf16_nt(const unsigned short* __restrict__ A,
                                                    const unsigned short* __restrict__ B,
                                                    float* __restrict__ C,
                                                    int M, int N, int K) {
  __shared__ __align__(16) unsigned short As[128 * 32];
  __shared__ __align__(16) unsigned short Bs[128 * 32];
  int tid = threadIdx.x;
  int wave = tid >> 6;
  int lane = tid & 63;
  int wm = wave >> 1, wn = wave & 1;
  int quad = lane >> 4, m16 = lane & 15;
  int row0 = blockIdx.y * 128, col0 = blockIdx.x * 128;

  floatx4 acc[4][4];
#pragma unroll
  for (int i = 0; i < 4; i++)
#pragma unroll
    for (int j = 0; j < 4; j++) acc[i][j] = (floatx4){0.f, 0.f, 0.f, 0.f};

  int c0 = tid, c1 = tid + 256;
  int r0c = c0 >> 2, q0c = (c0 & 3) * 8;
  int r1c = c1 >> 2, q1c = (c1 & 3) * 8;

  const size_t sK = (size_t)K;
  for (int k0 = 0; k0 < K; k0 += 32) {
    __builtin_amdgcn_global_load_lds(
        (const __attribute__((address_space(1))) unsigned int*)(A + (size_t)(row0 + r0c) * sK + k0 + q0c),
        (__attribute__((address_space(3))) unsigned int*)(As + c0 * 8), 16, 0, 0);
    __builtin_amdgcn_global_load_lds(
        (const __attribute__((address_space(1))) unsigned int*)(A + (size_t)(row0 + r1c) * sK + k0 + q1c),
        (__attribute__((address_space(3))) unsigned int*)(As + c1 * 8), 16, 0, 0);
    __builtin_amdgcn_global_load_lds(
        (const __attribute__((address_space(1))) unsigned int*)(B + (size_t)(col0 + r0c) * sK + k0 + q0c),
        (__attribute__((address_space(3))) unsigned int*)(Bs + c0 * 8), 16, 0, 0);
    __builtin_amdgcn_global_load_lds(
        (const __attribute__((address_space(1))) unsigned int*)(B + (size_t)(col0 + r1c) * sK + k0 + q1c),
        (__attribute__((address_space(3))) unsigned int*)(Bs + c1 * 8), 16, 0, 0);
    __syncthreads();

    bf16x8 af[4], bfr[4];
#pragma unroll
    for (int i = 0; i < 4; i++)
      af[i] = *(const bf16x8*)(As + (wm * 64 + i * 16 + m16) * 32 + quad * 8);
#pragma unroll
    for (int j = 0; j < 4; j++)
      bfr[j] = *(const bf16x8*)(Bs + (wn * 64 + j * 16 + m16) * 32 + quad * 8);
#pragma unroll
    for (int i = 0; i < 4; i++)
#pragma unroll
      for (int j = 0; j < 4; j++)
        acc[i][j] = __builtin_amdgcn_mfma_f32_16x16x32_bf16(af[i], bfr[j], acc[i][j], 0, 0, 0);
    __syncthreads();
  }

#pragma unroll
  for (int i = 0; i < 4; i++) {
#pragma unroll
    for (int j = 0; j < 4; j++) {
      int rr = row0 + wm * 64 + i * 16 + quad * 4;
      int cc = col0 + wn * 64 + j * 16 + m16;
#pragma unroll
      for (int r = 0; r < 4; r++)
        C[(size_t)(rr + r) * N + cc] = acc[i][j][r];
    }
  }
}

// ---------------- alpha -----------------------------------------------------
__global__ __launch_bounds__(256) void alpha_kernel(const float* __restrict__ x,
                                                    const float* __restrict__ W_alpha,
                                                    const float* __restrict__ b_alpha,
                                                    const float* __restrict__ alpha_base,
                                                    float* __restrict__ a_raw) {
  int gw = blockIdx.x * 4 + (threadIdx.x >> 6);
  int lane = threadIdx.x & 63;
  int h = gw >> 11;
  int t = gw & 2047;
  const float4* xr = (const float4*)(x + (size_t)t * DMODEL);
  const float4* wr = (const float4*)(W_alpha + (size_t)h * DMODEL);
  float s = 0.f;
  for (int i = lane; i < DMODEL / 4; i += 64) {
    float4 a = xr[i], b = wr[i];
    s += a.x * b.x + a.y * b.y + a.z * b.z + a.w * b.w;
  }
#pragma unroll
  for (int off = 32; off > 0; off >>= 1) s += __shfl_down(s, off);
  if (lane == 0) {
    float sig = 1.f / (1.f + expf(-(s + b_alpha[h])));
    a_raw[(size_t)h * SQLEN + t] = alpha_base[h] * 8.f * sig;
  }
}

// ---------------- cumsum ----------------------------------------------------
__global__ __launch_bounds__(256) void cumsum_kernel(const float* __restrict__ a_raw,
                                                     float* __restrict__ A) {
  int h = blockIdx.x;
  __shared__ float part[256];
  int tid = threadIdx.x;
  float v[8];
  float s = 0.f;
#pragma unroll
  for (int i = 0; i < 8; i++) {
    v[i] = a_raw[(size_t)h * SQLEN + tid * 8 + i];
    s += v[i];
  }
  part[tid] = s;
  __syncthreads();
  for (int off = 1; off < 256; off <<= 1) {
    float tmp = (tid >= off) ? part[tid - off] : 0.f;
    __syncthreads();
    part[tid] += tmp;
    __syncthreads();
  }
  float run = (tid > 0) ? part[tid - 1] : 0.f;
#pragma unroll
  for (int i = 0; i < 8; i++) {
    run += v[i];
    A[(size_t)h * SQLEN + tid * 8 + i] = run;
  }
}

// ---------------- xPos ------------------------------------------------------
__global__ __launch_bounds__(256) void xpos_kernel(const float* __restrict__ qkv,
                                                   const float* __restrict__ a_raw,
                                                   const int* __restrict__ offset_p,
                                                   float* __restrict__ q,
                                                   float* __restrict__ k,
                                                   float* __restrict__ v) {
  int idx = blockIdx.x * 256 + threadIdx.x;
  int j = idx & 63;
  int t = (idx >> 6) & 2047;
  int h = idx >> 17;
  float pos = (float)(t + offset_p[0]);
  float freq = exp2f(-(float)j * (13.287712379549449f / 64.f));
  float ang = pos * freq;
  float sn = sinf(ang), cs = cosf(ang);
  float zeta = (2.f * (float)j + 51.2f) / 179.2f;
  float lzp = log2f(zeta) * pos * (1.f / 512.f);
  float sc = exp2f(lzp);
  float sci = exp2f(-lzp);
  const float* row = qkv + (size_t)t * (3 * DMODEL);
  int base = h * DHEAD + j;
  float q1 = row[base], q2 = row[base + 64];
  float k1 = row[DMODEL + base], k2 = row[DMODEL + base + 64];
  float v1 = row[2 * DMODEL + base], v2 = row[2 * DMODEL + base + 64];
  size_t o = ((size_t)h * SQLEN + t) * DHEAD + j;
  q[o] = (q1 * cs - q2 * sn) * sc;
  q[o + 64] = (q2 * cs + q1 * sn) * sc;
  float km = (1.f - expf(a_raw[(size_t)h * SQLEN + t])) * sci;
  k[o] = (k1 * cs - k2 * sn) * km;
  k[o + 64] = (k2 * cs + k1 * sn) * km;
  v[o] = v1;
  v[o + 64] = v2;
}

// ---------------- transpose v -> vT bf16 [h][e][t] --------------------------
__global__ __launch_bounds__(256) void transpose_v_kernel(const float* __restrict__ v,
                                                          unsigned short* __restrict__ vT) {
  __shared__ float tile[64][65];
  int h = blockIdx.z, t0 = blockIdx.x * 64, e0 = blockIdx.y * 64;
  int tid = threadIdx.x;
  const float* src = v + ((size_t)h * SQLEN + t0) * DHEAD + e0;
#pragma unroll
  for (int p = 0; p < 4; p++) {
    int idx = tid + p * 256;
    int r = idx >> 4, c = (idx & 15) * 4;
    float4 f = *(const float4*)(src + (size_t)r * DHEAD + c);
    tile[r][c] = f.x; tile[r][c + 1] = f.y; tile[r][c + 2] = f.z; tile[r][c + 3] = f.w;
  }
  __syncthreads();
  unsigned short* dst = vT + (size_t)h * (DHEAD * SQLEN) + (size_t)e0 * SQLEN + t0;
#pragma unroll
  for (int p = 0; p < 2; p++) {
    int idx = tid + p * 256;
    int er = idx >> 3, toff = (idx & 7) * 8;
    bf16x8 o;
#pragma unroll
    for (int j = 0; j < 8; j++) o[j] = (short)f2bf(tile[toff + j][er]);
    *(bf16x8*)(dst + (size_t)er * SQLEN + toff) = o;
  }
}

// ---------------- transpose state -> stT bf16 [h][e][d] ---------------------
__global__ __launch_bounds__(256) void transpose_state_kernel(const float* __restrict__ st,
                                                              unsigned short* __restrict__ stT) {
  __shared__ float tile[64][65];
  int h = blockIdx.z, d0 = blockIdx.x * 64, e0 = blockIdx.y * 64;
  int tid = threadIdx.x;
  const float* src = st + (size_t)h * 16384 + (size_t)d0 * DHEAD + e0;
#pragma unroll
  for (int p = 0; p < 4; p++) {
    int idx = tid + p * 256;
    int r = idx >> 4, c = (idx & 15) * 4;
    float4 f = *(const float4*)(src + (size_t)r * DHEAD + c);
    tile[r][c] = f.x; tile[r][c + 1] = f.y; tile[r][c + 2] = f.z; tile[r][c + 3] = f.w;
  }
  __syncthreads();
  unsigned short* dst = stT + (size_t)h * 16384 + (size_t)e0 * DHEAD + d0;
#pragma unroll
  for (int p = 0; p < 2; p++) {
    int idx = tid + p * 256;
    int er = idx >> 3, doff = (idx & 7) * 8;
    bf16x8 o;
#pragma unroll
    for (int j = 0; j < 8; j++) o[j] = (short)f2bf(tile[doff + j][er]);
    *(bf16x8*)(dst + (size_t)er * DHEAD + doff) = o;
  }
}

// ---------------- retention: MFMA flash-style causal decay attention --------
// decay factored: exp(Ai-Aj) = exp(Ai-c) * exp(c-Aj), c=A[i0], baked into
// q/k bf16 staging scales. Cross term exp(Ai)*q@state = exp(c)*(q_s@stT).
__global__ __launch_bounds__(256) void retention_mfma(const float* __restrict__ q,
                                                      const float* __restrict__ k,
                                                      const unsigned short* __restrict__ vT,
                                                      const unsigned short* __restrict__ stT,
                                                      const float* __restrict__ A,
                                                      float* __restrict__ ret) {
  __shared__ __align__(16) unsigned short qs[64 * 136];
  __shared__ __align__(16) unsigned short ks[64 * 136];
  __shared__ __align__(16) unsigned short vs[128 * 72];
  __shared__ __align__(16) unsigned short Ss[64 * 72];
  int h = blockIdx.y;
  int i0 = blockIdx.x * 64;
  int tid = threadIdx.x;
  int wave = tid >> 6, lane = tid & 63, quad = lane >> 4, m16 = lane & 15;
  const float* Ah = A + (size_t)h * SQLEN;
  float c = Ah[i0];

  // stage q scaled by exp(A[i]-c), bf16
  const float* qh = q + ((size_t)h * SQLEN + i0) * DHEAD;
#pragma unroll
  for (int p = 0; p < 4; p++) {
    int g = tid + p * 256;
    int r = g >> 4, off = (g & 15) * 8;
    float w = __expf(Ah[i0 + r] - c);
    float4 f0 = *(const float4*)(qh + (size_t)r * DHEAD + off);
    float4 f1 = *(const float4*)(qh + (size_t)r * DHEAD + off + 4);
    bf16x8 o;
    o[0] = (short)f2bf(f0.x * w); o[1] = (short)f2bf(f0.y * w);
    o[2] = (short)f2bf(f0.z * w); o[3] = (short)f2bf(f0.w * w);
    o[4] = (short)f2bf(f1.x * w); o[5] = (short)f2bf(f1.y * w);
    o[6] = (short)f2bf(f1.z * w); o[7] = (short)f2bf(f1.w * w);
    *(bf16x8*)(qs + r * 136 + off) = o;
  }
  __syncthreads();

  bf16x8 qf[4];
#pragma unroll
  for (int dc = 0; dc < 4; dc++)
    qf[dc] = *(const bf16x8*)(qs + (wave * 16 + m16) * 136 + dc * 32 + quad * 8);

  floatx4 acc[8];
#pragma unroll
  for (int et = 0; et < 8; et++) acc[et] = (floatx4){0.f, 0.f, 0.f, 0.f};

  // cross term with initial state
  float ec = __expf(c);
  if (ec > 0.f) {
    const unsigned short* sp = stT + (size_t)h * 16384;
#pragma unroll
    for (int et = 0; et < 8; et++) {
#pragma unroll
      for (int dc = 0; dc < 4; dc++) {
        bf16x8 sf = *(const bf16x8*)(sp + (et * 16 + m16) * DHEAD + dc * 32 + quad * 8);
        acc[et] = __builtin_amdgcn_mfma_f32_16x16x32_bf16(qf[dc], sf, acc[et], 0, 0, 0);
      }
    }
#pragma unroll
    for (int et = 0; et < 8; et++) acc[et] = acc[et] * ec;
  }

  for (int j0 = 0; j0 <= i0; j0 += 64) {
    if (c - Ah[j0 + 63] < -88.f) continue;  // entire tile underflows to 0
    __syncthreads();
    // stage k scaled by exp(c-A[j])
    const float* kh = k + ((size_t)h * SQLEN + j0) * DHEAD;
#pragma unroll
    for (int p = 0; p < 4; p++) {
      int g = tid + p * 256;
      int r = g >> 4, off = (g & 15) * 8;
      float w = __expf(c - Ah[j0 + r]);
      float4 f0 = *(const float4*)(kh + (size_t)r * DHEAD + off);
      float4 f1 = *(const float4*)(kh + (size_t)r * DHEAD + off + 4);
      bf16x8 o;
      o[0] = (short)f2bf(f0.x * w); o[1] = (short)f2bf(f0.y * w);
      o[2] = (short)f2bf(f0.z * w); o[3] = (short)f2bf(f0.w * w);
      o[4] = (short)f2bf(f1.x * w); o[5] = (short)f2bf(f1.y * w);
      o[6] = (short)f2bf(f1.z * w); o[7] = (short)f2bf(f1.w * w);
      *(bf16x8*)(ks + r * 136 + off) = o;
    }
    // stage vT tile (rows e, 64 cols t)
    const unsigned short* vh = vT + (size_t)h * (DHEAD * SQLEN) + j0;
#pragma unroll
    for (int p = 0; p < 4; p++) {
      int idx = tid + p * 256;
      int e = idx >> 3, off = (idx & 7) * 8;
      *(bf16x8*)(vs + e * 72 + off) = *(const bf16x8*)(vh + (size_t)e * SQLEN + off);
    }
    __syncthreads();

    bool diag = (j0 == i0);
    int ii = i0 + wave * 16 + m16;
#pragma unroll
    for (int jt = 0; jt < 4; jt++) {
      floatx4 s = (floatx4){0.f, 0.f, 0.f, 0.f};
#pragma unroll
      for (int dc = 0; dc < 4; dc++) {
        bf16x8 kf = *(const bf16x8*)(ks + (jt * 16 + m16) * 136 + dc * 32 + quad * 8);
        s = __builtin_amdgcn_mfma_f32_16x16x32_bf16(kf, qf[dc], s, 0, 0, 0);
      }
      // lane holds S[w16+m16][jt*16+quad*4+r]; mask diag, cvt, write 8B
      int jb = j0 + jt * 16 + quad * 4;
      ushort4 pk;
      pk.x = f2bf((diag && (jb + 0 > ii)) ? 0.f : s[0]);
      pk.y = f2bf((diag && (jb + 1 > ii)) ? 0.f : s[1]);
      pk.z = f2bf((diag && (jb + 2 > ii)) ? 0.f : s[2]);
      pk.w = f2bf((diag && (jb + 3 > ii)) ? 0.f : s[3]);
      *(ushort4*)(Ss + (wave * 16 + m16) * 72 + jt * 16 + quad * 4) = pk;
    }

    // PV: wave-local S rows, no barrier needed
    bf16x8 sfr[2];
#pragma unroll
    for (int kc = 0; kc < 2; kc++)
      sfr[kc] = *(const bf16x8*)(Ss + (wave * 16 + m16) * 72 + kc * 32 + quad * 8);
#pragma unroll
    for (int et = 0; et < 8; et++) {
#pragma unroll
      for (int kc = 0; kc < 2; kc++) {
        bf16x8 vf = *(const bf16x8*)(vs + (et * 16 + m16) * 72 + kc * 32 + quad * 8);
        acc[et] = __builtin_amdgcn_mfma_f32_16x16x32_bf16(sfr[kc], vf, acc[et], 0, 0, 0);
      }
    }
  }

#pragma unroll
  for (int et = 0; et < 8; et++) {
    int col = h * DHEAD + et * 16 + m16;
#pragma unroll
    for (int r = 0; r < 4; r++) {
      int row = i0 + wave * 16 + quad * 4 + r;
      ret[(size_t)row * DMODEL + col] = acc[et][r];
    }
  }
}

// ---------------- new_state partials ----------------------------------------
__global__ __launch_bounds__(256) void state_partial(const float* __restrict__ k,
                                                     const float* __restrict__ v,
                                                     const float* __restrict__ A,
                                                     float* __restrict__ P) {
  int h = blockIdx.y, c = blockIdx.x;
  int tid = threadIdx.x;
  __shared__ float kb[4][128];
  __shared__ float vb[4][128];
  float B = A[(size_t)h * SQLEN + SQLEN - 1];
  int d0 = (tid >> 4) << 3;
  int e0 = (tid & 15) << 3;
  float acc[8][8];
#pragma unroll
  for (int a = 0; a < 8; a++)
#pragma unroll
    for (int b = 0; b < 8; b++) acc[a][b] = 0.f;

  for (int j0 = c * 128; j0 < c * 128 + 128; j0 += 4) {
    for (int l = tid; l < 512; l += 256) {
      int jj = l >> 7, d = l & 127;
      int j = j0 + jj;
      float w = __expf(B - A[(size_t)h * SQLEN + j]);
      kb[jj][d] = k[((size_t)h * SQLEN + j) * DHEAD + d] * w;
      vb[jj][d] = v[((size_t)h * SQLEN + j) * DHEAD + d];
    }
    __syncthreads();
#pragma unroll
    for (int jj = 0; jj < 4; jj++) {
      float4 k0 = *(const float4*)(&kb[jj][d0]);
      float4 k1 = *(const float4*)(&kb[jj][d0 + 4]);
      float4 v0 = *(const float4*)(&vb[jj][e0]);
      float4 v1 = *(const float4*)(&vb[jj][e0 + 4]);
      float kr[8] = {k0.x, k0.y, k0.z, k0.w, k1.x, k1.y, k1.z, k1.w};
      float vr[8] = {v0.x, v0.y, v0.z, v0.w, v1.x, v1.y, v1.z, v1.w};
#pragma unroll
      for (int a = 0; a < 8; a++)
#pragma unroll
        for (int b = 0; b < 8; b++) acc[a][b] += kr[a] * vr[b];
    }
    __syncthreads();
  }
  float* Pp = P + (size_t)(h * 16 + c) * 16384;
#pragma unroll
  for (int a = 0; a < 8; a++) {
    float* prow = Pp + (size_t)(d0 + a) * 128 + e0;
    float4 o0 = {acc[a][0], acc[a][1], acc[a][2], acc[a][3]};
    float4 o1 = {acc[a][4], acc[a][5], acc[a][6], acc[a][7]};
    *(float4*)(prow) = o0;
    *(float4*)(prow + 4) = o1;
  }
}

__global__ __launch_bounds__(256) void state_combine(const float* __restrict__ P,
                                                     const float* __restrict__ state,
                                                     const float* __restrict__ A,
                                                     float* __restrict__ out_state) {
  int idx = blockIdx.x * 256 + threadIdx.x;
  int h = idx >> 14;
  int de = idx & 16383;
  float B = A[(size_t)h * SQLEN + SQLEN - 1];
  float s = __expf(B) * state[idx];
#pragma unroll
  for (int c = 0; c < 16; c++) s += P[(size_t)(h * 16 + c) * 16384 + de];
  out_state[idx] = s;
}

// ---------------- group norm ------------------------------------------------
__global__ __launch_bounds__(256) void groupnorm_kernel(const float* __restrict__ ret,
                                                        const float* __restrict__ w,
                                                        const float* __restrict__ b,
                                                        float* __restrict__ out) {
  int gw = blockIdx.x * 4 + (threadIdx.x >> 6);
  int lane = threadIdx.x & 63;
  int t = gw >> 4, h = gw & 15;
  const float* p = ret + (size_t)t * DMODEL + h * DHEAD;
  float x0 = p[lane], x1 = p[lane + 64];
  float s = x0 + x1, ss = x0 * x0 + x1 * x1;
#pragma unroll
  for (int off = 32; off > 0; off >>= 1) {
    s += __shfl_xor(s, off);
    ss += __shfl_xor(ss, off);
  }
  float mu = s * (1.f / 128.f);
  float var = ss * (1.f / 128.f) - mu * mu;
  float inv = rsqrtf(var + 1e-5f);
  int cidx = h * DHEAD + lane;
  float* o = out + (size_t)t * DMODEL;
  o[cidx] = (x0 - mu) * inv * w[cidx] + b[cidx];
  o[cidx + 64] = (x1 - mu) * inv * w[cidx + 64] + b[cidx + 64];
}

// ---------------- swish(G) * ret_n ------------------------------------------
__global__ __launch_bounds__(256) void swishmul_kernel(const float* __restrict__ G,
                                                       const float* __restrict__ rn,
                                                       float* __restrict__ H) {
  int i = blockIdx.x * 256 + threadIdx.x;
  float4 g = ((const float4*)G)[i];
  float4 r = ((const float4*)rn)[i];
  float4 o;
  o.x = g.x / (1.f + expf(-g.x)) * r.x;
  o.y = g.y / (1.f + expf(-g.y)) * r.y;
  o.z = g.z / (1.f + expf(-g.z)) * r.z;
  o.w = g.w / (1.f + expf(-g.w)) * r.w;
  ((float4*)H)[i] = o;
}

extern "C" void kernel_launch(void* const* d_in, const int* in_sizes, int n_in,
                              void* d_out, int out_size, void* d_ws, size_t ws_size,
                              hipStream_t stream) {
  const float* x = (const float*)d_in[0];
  const float* state = (const float*)d_in[1];
  const float* W_qkv = (const float*)d_in[2];
  const float* W_alpha = (const float*)d_in[3];
  const float* b_alpha = (const float*)d_in[4];
  const float* alpha_base = (const float*)d_in[5];
  const float* gn_w = (const float*)d_in[6];
  const float* gn_b = (const float*)d_in[7];
  const float* W_out = (const float*)d_in[8];
  const float* W_gate = (const float*)d_in[9];
  const int* offset = (const int*)d_in[10];

  float* ws = (float*)d_ws;
  float* qkv = ws;                    // [0, 12.58M) alive gemm1 -> xpos
  float* G   = ws;                    // overlay on dead qkv
  float* H   = ws + 4194304;          // overlay
  float* P   = ws + 8388608;          // overlay
  float* q   = ws + 12582912;
  float* k   = ws + 16777216;
  float* v   = ws + 20971520;
  float* ret = ws + 25165824;
  float* rn  = ws + 29360128;         // written by groupnorm (late)
  float* araw = ws + 33554432;
  float* Acum = ws + 33587200;

  // bf16 overlays:
  unsigned short* xb    = (unsigned short*)(ws + 12582912);  // pre-xpos over q
  unsigned short* Wqkvb = (unsigned short*)(ws + 16777216);  // pre-xpos over k+v
  // vT/stT overlay the rn region (dead until groupnorm, consumed by retention)
  unsigned short* vT_b  = (unsigned short*)(ws + 29360128);  // 4.19M bf16
  unsigned short* stT_b = (unsigned short*)(ws + 31457280);  // 262K bf16
  // phase 2 (post-retention/state): over q/k regions
  unsigned short* rnb    = (unsigned short*)(ws + 12582912);
  unsigned short* Wgateb = (unsigned short*)(ws + 14680064);
  unsigned short* Woutb  = (unsigned short*)(ws + 16777216);
  unsigned short* Hb     = (unsigned short*)(ws + 18874368);

  float* out = (float*)d_out;
  float* out_state = out + 4194304;

  dim3 blk(256);
  f2b_kernel<<<dim3(4096), blk, 0, stream>>>((const float4*)x, (ushort4*)xb);
  f2b_kernel<<<dim3(12288), blk, 0, stream>>>((const float4*)W_qkv, (ushort4*)Wqkvb);
  gemm_bf16_nt<<<dim3(48, 16), blk, 0, stream>>>(xb, Wqkvb, qkv, 2048, 6144, 2048);

  alpha_kernel<<<dim3(8192), blk, 0, stream>>>(x, W_alpha, b_alpha, alpha_base, araw);
  cumsum_kernel<<<dim3(16), blk, 0, stream>>>(araw, Acum);
  xpos_kernel<<<dim3(8192), blk, 0, stream>>>(qkv, araw, offset, q, k, v);
  transpose_v_kernel<<<dim3(32, 2, 16), blk, 0, stream>>>(v, vT_b);
  transpose_state_kernel<<<dim3(2, 2, 16), blk, 0, stream>>>(state, stT_b);

  retention_mfma<<<dim3(32, 16), blk, 0, stream>>>(q, k, vT_b, stT_b, Acum, ret);
  state_partial<<<dim3(16, 16), blk, 0, stream>>>(k, v, Acum, P);
  state_combine<<<dim3(1024), blk, 0, stream>>>(P, state, Acum, out_state);
  groupnorm_kernel<<<dim3(8192), blk, 0, stream>>>(ret, gn_w, gn_b, rn);

  f2b_kernel<<<dim3(4096), blk, 0, stream>>>((const float4*)rn, (ushort4*)rnb);
  f2b_kernel<<<dim3(4096), blk, 0, stream>>>((const float4*)W_gate, (ushort4*)Wgateb);
  f2b_kernel<<<dim3(4096), blk, 0, stream>>>((const float4*)W_out, (ushort4*)Woutb);
  gemm_bf16_nt<<<dim3(16, 16), blk, 0, stream>>>(rnb, Wgateb, G, 2048, 2048, 2048);
  swishmul_kernel<<<dim3(4096), blk, 0, stream>>>(G, rn, H);
  f2b_kernel<<<dim3(4096), blk, 0, stream>>>((const float4*)H, (ushort4*)Hb);
  gemm_bf16_nt<<<dim3(16, 16), blk, 0, stream>>>(Hb, Woutb, out, 2048, 2048, 2048);
}

// Round 4
// 449.670 us; speedup vs baseline: 6.0542x; 1.1743x over previous
//
#include <hip/hip_runtime.h>
#include <cstddef>

#define SQLEN 2048
#define DMODEL 2048
#define NHEADS 16
#define DHEAD 128

typedef __attribute__((ext_vector_type(8))) short bf16x8;
typedef __attribute__((ext_vector_type(4))) float floatx4;

__device__ __forceinline__ unsigned short f2bf(float f) {
  union { float f; unsigned u; } c; c.f = f;
  unsigned u = c.u;
  unsigned r = u + 0x7fffu + ((u >> 16) & 1u);
  return (unsigned short)(r >> 16);
}
__device__ __forceinline__ float bf2f(unsigned short s) {
  union { unsigned u; float f; } c; c.u = ((unsigned)s) << 16;
  return c.f;
}

// ---------------- fp32 -> bf16 convert (vectorized) -------------------------
__global__ __launch_bounds__(256) void f2b_kernel(const float4* __restrict__ in,
                                                  ushort4* __restrict__ out) {
  int i = blockIdx.x * 256 + threadIdx.x;
  float4 v = in[i];
  ushort4 o;
  o.x = f2bf(v.x); o.y = f2bf(v.y); o.z = f2bf(v.z); o.w = f2bf(v.w);
  out[i] = o;
}

// ---------------- bf16 MFMA GEMM: C[M,N] = A[M,K] @ B[N,K]^T ----------------
__global__ __launch_bounds__(256) void gemm_bf16_nt(const unsigned short* __restrict__ A,
                                                    const unsigned short* __restrict__ B,
                                                    float* __restrict__ C,
                                                    int M, int N, int K) {
  __shared__ __align__(16) unsigned short As[128 * 32];
  __shared__ __align__(16) unsigned short Bs[128 * 32];
  int tid = threadIdx.x;
  int wave = tid >> 6;
  int lane = tid & 63;
  int wm = wave >> 1, wn = wave & 1;
  int quad = lane >> 4, m16 = lane & 15;
  int row0 = blockIdx.y * 128, col0 = blockIdx.x * 128;

  floatx4 acc[4][4];
#pragma unroll
  for (int i = 0; i < 4; i++)
#pragma unroll
    for (int j = 0; j < 4; j++) acc[i][j] = (floatx4){0.f, 0.f, 0.f, 0.f};

  int c0 = tid, c1 = tid + 256;
  int r0c = c0 >> 2, q0c = (c0 & 3) * 8;
  int r1c = c1 >> 2, q1c = (c1 & 3) * 8;

  const size_t sK = (size_t)K;
  for (int k0 = 0; k0 < K; k0 += 32) {
    __builtin_amdgcn_global_load_lds(
        (const __attribute__((address_space(1))) unsigned int*)(A + (size_t)(row0 + r0c) * sK + k0 + q0c),
        (__attribute__((address_space(3))) unsigned int*)(As + c0 * 8), 16, 0, 0);
    __builtin_amdgcn_global_load_lds(
        (const __attribute__((address_space(1))) unsigned int*)(A + (size_t)(row0 + r1c) * sK + k0 + q1c),
        (__attribute__((address_space(3))) unsigned int*)(As + c1 * 8), 16, 0, 0);
    __builtin_amdgcn_global_load_lds(
        (const __attribute__((address_space(1))) unsigned int*)(B + (size_t)(col0 + r0c) * sK + k0 + q0c),
        (__attribute__((address_space(3))) unsigned int*)(Bs + c0 * 8), 16, 0, 0);
    __builtin_amdgcn_global_load_lds(
        (const __attribute__((address_space(1))) unsigned int*)(B + (size_t)(col0 + r1c) * sK + k0 + q1c),
        (__attribute__((address_space(3))) unsigned int*)(Bs + c1 * 8), 16, 0, 0);
    __syncthreads();

    bf16x8 af[4], bfr[4];
#pragma unroll
    for (int i = 0; i < 4; i++)
      af[i] = *(const bf16x8*)(As + (wm * 64 + i * 16 + m16) * 32 + quad * 8);
#pragma unroll
    for (int j = 0; j < 4; j++)
      bfr[j] = *(const bf16x8*)(Bs + (wn * 64 + j * 16 + m16) * 32 + quad * 8);
#pragma unroll
    for (int i = 0; i < 4; i++)
#pragma unroll
      for (int j = 0; j < 4; j++)
        acc[i][j] = __builtin_amdgcn_mfma_f32_16x16x32_bf16(af[i], bfr[j], acc[i][j], 0, 0, 0);
    __syncthreads();
  }

#pragma unroll
  for (int i = 0; i < 4; i++) {
#pragma unroll
    for (int j = 0; j < 4; j++) {
      int rr = row0 + wm * 64 + i * 16 + quad * 4;
      int cc = col0 + wn * 64 + j * 16 + m16;
#pragma unroll
      for (int r = 0; r < 4; r++)
        C[(size_t)(rr + r) * N + cc] = acc[i][j][r];
    }
  }
}

// ---------------- alpha v2: block = 4 t-rows staged in LDS, loop 16 heads ---
__global__ __launch_bounds__(256) void alpha_kernel(const float* __restrict__ x,
                                                    const float* __restrict__ W_alpha,
                                                    const float* __restrict__ b_alpha,
                                                    const float* __restrict__ alpha_base,
                                                    float* __restrict__ a_raw) {
  __shared__ float xs[4][2048];
  int tid = threadIdx.x;
  int t0 = blockIdx.x * 4;
#pragma unroll
  for (int p = 0; p < 8; p++) {
    int idx = tid + p * 256;                 // 2048 float4
    int row = idx >> 9, c4 = idx & 511;
    *(float4*)&xs[row][c4 * 4] = *(const float4*)(x + (size_t)(t0 + row) * DMODEL + c4 * 4);
  }
  __syncthreads();
  int w = tid >> 6, lane = tid & 63;
  int t = t0 + w;
#pragma unroll
  for (int h = 0; h < NHEADS; h++) {
    const float4* wr = (const float4*)(W_alpha + (size_t)h * DMODEL);
    float s = 0.f;
#pragma unroll
    for (int i = lane; i < 512; i += 64) {
      float4 a = *(const float4*)&xs[w][i * 4];
      float4 b = wr[i];
      s += a.x * b.x + a.y * b.y + a.z * b.z + a.w * b.w;
    }
#pragma unroll
    for (int off = 32; off > 0; off >>= 1) s += __shfl_down(s, off);
    if (lane == 0) {
      float sig = 1.f / (1.f + expf(-(s + b_alpha[h])));
      a_raw[(size_t)h * SQLEN + t] = alpha_base[h] * 8.f * sig;
    }
  }
}

// ---------------- cumsum ----------------------------------------------------
__global__ __launch_bounds__(256) void cumsum_kernel(const float* __restrict__ a_raw,
                                                     float* __restrict__ A) {
  int h = blockIdx.x;
  __shared__ float part[256];
  int tid = threadIdx.x;
  float v[8];
  float s = 0.f;
#pragma unroll
  for (int i = 0; i < 8; i++) {
    v[i] = a_raw[(size_t)h * SQLEN + tid * 8 + i];
    s += v[i];
  }
  part[tid] = s;
  __syncthreads();
  for (int off = 1; off < 256; off <<= 1) {
    float tmp = (tid >= off) ? part[tid - off] : 0.f;
    __syncthreads();
    part[tid] += tmp;
    __syncthreads();
  }
  float run = (tid > 0) ? part[tid - 1] : 0.f;
#pragma unroll
  for (int i = 0; i < 8; i++) {
    run += v[i];
    A[(size_t)h * SQLEN + tid * 8 + i] = run;
  }
}

// ---------------- xPos: emit q,k,v directly as bf16 [h][t][d] ---------------
__global__ __launch_bounds__(256) void xpos_kernel(const float* __restrict__ qkv,
                                                   const float* __restrict__ a_raw,
                                                   const int* __restrict__ offset_p,
                                                   unsigned short* __restrict__ qb,
                                                   unsigned short* __restrict__ kb,
                                                   unsigned short* __restrict__ vb) {
  int idx = blockIdx.x * 256 + threadIdx.x;
  int j = idx & 63;
  int t = (idx >> 6) & 2047;
  int h = idx >> 17;
  float pos = (float)(t + offset_p[0]);
  float freq = exp2f(-(float)j * (13.287712379549449f / 64.f));
  float ang = pos * freq;
  float sn = sinf(ang), cs = cosf(ang);
  float zeta = (2.f * (float)j + 51.2f) / 179.2f;
  float lzp = log2f(zeta) * pos * (1.f / 512.f);
  float sc = exp2f(lzp);
  float sci = exp2f(-lzp);
  const float* row = qkv + (size_t)t * (3 * DMODEL);
  int base = h * DHEAD + j;
  float q1 = row[base], q2 = row[base + 64];
  float k1 = row[DMODEL + base], k2 = row[DMODEL + base + 64];
  float v1 = row[2 * DMODEL + base], v2 = row[2 * DMODEL + base + 64];
  size_t o = ((size_t)h * SQLEN + t) * DHEAD + j;
  qb[o] = f2bf((q1 * cs - q2 * sn) * sc);
  qb[o + 64] = f2bf((q2 * cs + q1 * sn) * sc);
  float km = (1.f - expf(a_raw[(size_t)h * SQLEN + t])) * sci;
  kb[o] = f2bf((k1 * cs - k2 * sn) * km);
  kb[o + 64] = f2bf((k2 * cs + k1 * sn) * km);
  vb[o] = f2bf(v1);
  vb[o + 64] = f2bf(v2);
}

// ------- transpose kb/vb [h][t][d] -> [h][d][t]; k gets exp(B-A[t]) scale ---
__global__ __launch_bounds__(256) void transpose_kv_kernel(const unsigned short* __restrict__ kb,
                                                           const unsigned short* __restrict__ vb,
                                                           const float* __restrict__ A,
                                                           unsigned short* __restrict__ kT,
                                                           unsigned short* __restrict__ vT) {
  __shared__ __align__(16) unsigned short tile[64][72];
  int h = blockIdx.z >> 1, sel = blockIdx.z & 1;
  int t0 = blockIdx.x * 64, d0 = blockIdx.y * 64;
  int tid = threadIdx.x;
  const unsigned short* src = (sel ? vb : kb) + ((size_t)h * SQLEN + t0) * DHEAD + d0;
  unsigned short* dst = (sel ? vT : kT) + (size_t)h * (DHEAD * SQLEN) + (size_t)d0 * SQLEN + t0;
  float B = A[(size_t)h * SQLEN + SQLEN - 1];
#pragma unroll
  for (int p = 0; p < 2; p++) {
    int c = tid + p * 256;              // 512 chunks of 8
    int r = c >> 3, off = (c & 7) * 8;
    bf16x8 in = *(const bf16x8*)(src + (size_t)r * DHEAD + off);
    if (!sel) {
      float w = __expf(B - A[(size_t)h * SQLEN + t0 + r]);
      bf16x8 o;
#pragma unroll
      for (int j = 0; j < 8; j++) o[j] = (short)f2bf(bf2f((unsigned short)in[j]) * w);
      *(bf16x8*)&tile[r][off] = o;
    } else {
      *(bf16x8*)&tile[r][off] = in;
    }
  }
  __syncthreads();
#pragma unroll
  for (int p = 0; p < 2; p++) {
    int c = tid + p * 256;
    int dr = c >> 3, toff = (c & 7) * 8;
    bf16x8 o;
#pragma unroll
    for (int j = 0; j < 8; j++) o[j] = (short)tile[toff + j][dr];
    *(bf16x8*)(dst + (size_t)dr * SQLEN + toff) = o;
  }
}

// ---------------- transpose state -> stT bf16 [h][e][d] ---------------------
__global__ __launch_bounds__(256) void transpose_state_kernel(const float* __restrict__ st,
                                                              unsigned short* __restrict__ stT) {
  __shared__ float tile[64][65];
  int h = blockIdx.z, d0 = blockIdx.x * 64, e0 = blockIdx.y * 64;
  int tid = threadIdx.x;
  const float* src = st + (size_t)h * 16384 + (size_t)d0 * DHEAD + e0;
#pragma unroll
  for (int p = 0; p < 4; p++) {
    int idx = tid + p * 256;
    int r = idx >> 4, c = (idx & 15) * 4;
    float4 f = *(const float4*)(src + (size_t)r * DHEAD + c);
    tile[r][c] = f.x; tile[r][c + 1] = f.y; tile[r][c + 2] = f.z; tile[r][c + 3] = f.w;
  }
  __syncthreads();
  unsigned short* dst = stT + (size_t)h * 16384 + (size_t)e0 * DHEAD + d0;
#pragma unroll
  for (int p = 0; p < 2; p++) {
    int idx = tid + p * 256;
    int er = idx >> 3, doff = (idx & 7) * 8;
    bf16x8 o;
#pragma unroll
    for (int j = 0; j < 8; j++) o[j] = (short)f2bf(tile[doff + j][er]);
    *(bf16x8*)(dst + (size_t)er * DHEAD + doff) = o;
  }
}

// ---------------- retention v2: pure global_load_lds staging, decay on S ----
// S*Delta = (q.k) * exp(Ai-c) * exp(c-Aj); ei per lane, dj from LDS table.
// Grid: x = h (fast, XCD L2 locality), y = i0 tile.
__global__ __launch_bounds__(256) void retention_mfma(const unsigned short* __restrict__ qb,
                                                      const unsigned short* __restrict__ kb,
                                                      const unsigned short* __restrict__ vT,
                                                      const unsigned short* __restrict__ stT,
                                                      const float* __restrict__ A,
                                                      float* __restrict__ ret) {
  __shared__ __align__(16) unsigned short qs[64 * 128];
  __shared__ __align__(16) unsigned short ks[64 * 128];
  __shared__ __align__(16) unsigned short vs[128 * 64];
  __shared__ __align__(16) unsigned short Ss[64 * 72];
  __shared__ float djs[64];
  int h = blockIdx.x;
  int i0 = blockIdx.y * 64;
  int tid = threadIdx.x;
  int wave = tid >> 6, lane = tid & 63, quad = lane >> 4, m16 = lane & 15;
  const float* Ah = A + (size_t)h * SQLEN;
  float c = Ah[i0];

  // stage q tile (bf16, XOR-swizzled chunks to break LDS bank aliasing)
  const unsigned short* qh = qb + ((size_t)h * SQLEN + i0) * DHEAD;
#pragma unroll
  for (int p = 0; p < 4; p++) {
    int cch = tid + p * 256;
    int r = cch >> 4, kp = (cch & 15) ^ (r & 7);
    __builtin_amdgcn_global_load_lds(
        (const __attribute__((address_space(1))) unsigned int*)(qh + (size_t)r * DHEAD + kp * 8),
        (__attribute__((address_space(3))) unsigned int*)(qs + cch * 8), 16, 0, 0);
  }
  __syncthreads();

  int rq = wave * 16 + m16;
  bf16x8 qf[4];
#pragma unroll
  for (int dc = 0; dc < 4; dc++)
    qf[dc] = *(const bf16x8*)(qs + rq * 128 + (((dc * 4 + quad) ^ (rq & 7)) * 8));
  float ei = __expf(Ah[i0 + rq] - c);

  floatx4 acc[8];
#pragma unroll
  for (int et = 0; et < 8; et++) acc[et] = (floatx4){0.f, 0.f, 0.f, 0.f};

  // cross term with initial state: exp(Ai) * q @ stT
  if (c > -87.f) {
    const unsigned short* sp = stT + (size_t)h * 16384;
    float ecr[4];
#pragma unroll
    for (int r = 0; r < 4; r++) ecr[r] = __expf(Ah[i0 + wave * 16 + quad * 4 + r]);
#pragma unroll
    for (int et = 0; et < 8; et++) {
#pragma unroll
      for (int dc = 0; dc < 4; dc++) {
        bf16x8 sf = *(const bf16x8*)(sp + (et * 16 + m16) * DHEAD + dc * 32 + quad * 8);
        acc[et] = __builtin_amdgcn_mfma_f32_16x16x32_bf16(qf[dc], sf, acc[et], 0, 0, 0);
      }
#pragma unroll
      for (int r = 0; r < 4; r++) acc[et][r] *= ecr[r];
    }
  }

  for (int j0 = 0; j0 <= i0; j0 += 64) {
    if (c - Ah[j0 + 63] < -87.f) continue;  // whole tile underflows
    __syncthreads();
    const unsigned short* kh = kb + ((size_t)h * SQLEN + j0) * DHEAD;
    const unsigned short* vh = vT + (size_t)h * (DHEAD * SQLEN) + j0;
#pragma unroll
    for (int p = 0; p < 4; p++) {
      int cch = tid + p * 256;
      int r = cch >> 4, kp = (cch & 15) ^ (r & 7);
      __builtin_amdgcn_global_load_lds(
          (const __attribute__((address_space(1))) unsigned int*)(kh + (size_t)r * DHEAD + kp * 8),
          (__attribute__((address_space(3))) unsigned int*)(ks + cch * 8), 16, 0, 0);
      int e = cch >> 3, tp = (cch & 7) ^ (e & 7);
      __builtin_amdgcn_global_load_lds(
          (const __attribute__((address_space(1))) unsigned int*)(vh + (size_t)e * SQLEN + tp * 8),
          (__attribute__((address_space(3))) unsigned int*)(vs + cch * 8), 16, 0, 0);
    }
    if (tid < 64) djs[tid] = __expf(c - Ah[j0 + tid]);
    __syncthreads();

    bool diag = (j0 == i0);
    int ii = rq;  // i within tile
#pragma unroll
    for (int jt = 0; jt < 4; jt++) {
      floatx4 s = (floatx4){0.f, 0.f, 0.f, 0.f};
#pragma unroll
      for (int dc = 0; dc < 4; dc++) {
        int rk = jt * 16 + m16;
        bf16x8 kf = *(const bf16x8*)(ks + rk * 128 + (((dc * 4 + quad) ^ (rk & 7)) * 8));
        s = __builtin_amdgcn_mfma_f32_16x16x32_bf16(kf, qf[dc], s, 0, 0, 0);
      }
      int jb = jt * 16 + quad * 4;
      float4 dj4 = *(const float4*)&djs[jb];
      ushort4 pk;
      pk.x = f2bf((diag && (jb + 0 > ii)) ? 0.f : s[0] * ei * dj4.x);
      pk.y = f2bf((diag && (jb + 1 > ii)) ? 0.f : s[1] * ei * dj4.y);
      pk.z = f2bf((diag && (jb + 2 > ii)) ? 0.f : s[2] * ei * dj4.z);
      pk.w = f2bf((diag && (jb + 3 > ii)) ? 0.f : s[3] * ei * dj4.w);
      *(ushort4*)(Ss + rq * 72 + jb) = pk;
    }

    // PV (wave-local S rows)
    bf16x8 sfr[2];
#pragma unroll
    for (int kc = 0; kc < 2; kc++)
      sfr[kc] = *(const bf16x8*)(Ss + rq * 72 + kc * 32 + quad * 8);
#pragma unroll
    for (int et = 0; et < 8; et++) {
#pragma unroll
      for (int kc = 0; kc < 2; kc++) {
        int e = et * 16 + m16;
        bf16x8 vf = *(const bf16x8*)(vs + e * 64 + (((kc * 4 + quad) ^ (e & 7)) * 8));
        acc[et] = __builtin_amdgcn_mfma_f32_16x16x32_bf16(sfr[kc], vf, acc[et], 0, 0, 0);
      }
    }
  }

#pragma unroll
  for (int et = 0; et < 8; et++) {
    int col = h * DHEAD + et * 16 + m16;
#pragma unroll
    for (int r = 0; r < 4; r++) {
      int row = i0 + wave * 16 + quad * 4 + r;
      ret[(size_t)row * DMODEL + col] = acc[et][r];
    }
  }
}

// -------- new_state GEMM: P[h,chunk] = kT_s[:,krange] @ vT[:,krange]^T ------
__global__ __launch_bounds__(256) void state_gemm(const unsigned short* __restrict__ kT,
                                                  const unsigned short* __restrict__ vT,
                                                  float* __restrict__ P) {
  __shared__ __align__(16) unsigned short As[128 * 32];
  __shared__ __align__(16) unsigned short Bs[128 * 32];
  int chunk = blockIdx.x, h = blockIdx.y;
  int tid = threadIdx.x;
  int wave = tid >> 6, lane = tid & 63;
  int wm = wave >> 1, wn = wave & 1;
  int quad = lane >> 4, m16 = lane & 15;
  const unsigned short* Ab = kT + (size_t)h * (DHEAD * SQLEN);
  const unsigned short* Bb = vT + (size_t)h * (DHEAD * SQLEN);

  floatx4 acc[4][4];
#pragma unroll
  for (int i = 0; i < 4; i++)
#pragma unroll
    for (int j = 0; j < 4; j++) acc[i][j] = (floatx4){0.f, 0.f, 0.f, 0.f};

  int c0 = tid, c1 = tid + 256;
  int r0c = c0 >> 2, q0c = (c0 & 3) * 8;
  int r1c = c1 >> 2, q1c = (c1 & 3) * 8;

  for (int k0 = chunk * 256; k0 < chunk * 256 + 256; k0 += 32) {
    __builtin_amdgcn_global_load_lds(
        (const __attribute__((address_space(1))) unsigned int*)(Ab + (size_t)r0c * SQLEN + k0 + q0c),
        (__attribute__((address_space(3))) unsigned int*)(As + c0 * 8), 16, 0, 0);
    __builtin_amdgcn_global_load_lds(
        (const __attribute__((address_space(1))) unsigned int*)(Ab + (size_t)r1c * SQLEN + k0 + q1c),
        (__attribute__((address_space(3))) unsigned int*)(As + c1 * 8), 16, 0, 0);
    __builtin_amdgcn_global_load_lds(
        (const __attribute__((address_space(1))) unsigned int*)(Bb + (size_t)r0c * SQLEN + k0 + q0c),
        (__attribute__((address_space(3))) unsigned int*)(Bs + c0 * 8), 16, 0, 0);
    __builtin_amdgcn_global_load_lds(
        (const __attribute__((address_space(1))) unsigned int*)(Bb + (size_t)r1c * SQLEN + k0 + q1c),
        (__attribute__((address_space(3))) unsigned int*)(Bs + c1 * 8), 16, 0, 0);
    __syncthreads();

    bf16x8 af[4], bfr[4];
#pragma unroll
    for (int i = 0; i < 4; i++)
      af[i] = *(const bf16x8*)(As + (wm * 64 + i * 16 + m16) * 32 + quad * 8);
#pragma unroll
    for (int j = 0; j < 4; j++)
      bfr[j] = *(const bf16x8*)(Bs + (wn * 64 + j * 16 + m16) * 32 + quad * 8);
#pragma unroll
    for (int i = 0; i < 4; i++)
#pragma unroll
      for (int j = 0; j < 4; j++)
        acc[i][j] = __builtin_amdgcn_mfma_f32_16x16x32_bf16(af[i], bfr[j], acc[i][j], 0, 0, 0);
    __syncthreads();
  }

  float* Pp = P + (size_t)(h * 8 + chunk) * 16384;
#pragma unroll
  for (int i = 0; i < 4; i++)
#pragma unroll
    for (int j = 0; j < 4; j++) {
      int rr = wm * 64 + i * 16 + quad * 4;
      int cc = wn * 64 + j * 16 + m16;
#pragma unroll
      for (int r = 0; r < 4; r++)
        Pp[(size_t)(rr + r) * DHEAD + cc] = acc[i][j][r];
    }
}

__global__ __launch_bounds__(256) void state_combine(const float* __restrict__ P,
                                                     const float* __restrict__ state,
                                                     const float* __restrict__ A,
                                                     float* __restrict__ out_state) {
  int idx = blockIdx.x * 256 + threadIdx.x;  // 16*16384
  int h = idx >> 14;
  int de = idx & 16383;
  float B = A[(size_t)h * SQLEN + SQLEN - 1];
  float s = __expf(B) * state[idx];
#pragma unroll
  for (int c = 0; c < 8; c++) s += P[(size_t)(h * 8 + c) * 16384 + de];
  out_state[idx] = s;
}

// ---------------- group norm (emits fp32 + bf16) ----------------------------
__global__ __launch_bounds__(256) void groupnorm_kernel(const float* __restrict__ ret,
                                                        const float* __restrict__ w,
                                                        const float* __restrict__ b,
                                                        float* __restrict__ out,
                                                        unsigned short* __restrict__ outb) {
  int gw = blockIdx.x * 4 + (threadIdx.x >> 6);
  int lane = threadIdx.x & 63;
  int t = gw >> 4, h = gw & 15;
  const float* p = ret + (size_t)t * DMODEL + h * DHEAD;
  float x0 = p[lane], x1 = p[lane + 64];
  float s = x0 + x1, ss = x0 * x0 + x1 * x1;
#pragma unroll
  for (int off = 32; off > 0; off >>= 1) {
    s += __shfl_xor(s, off);
    ss += __shfl_xor(ss, off);
  }
  float mu = s * (1.f / 128.f);
  float var = ss * (1.f / 128.f) - mu * mu;
  float inv = rsqrtf(var + 1e-5f);
  int cidx = h * DHEAD + lane;
  float r0 = (x0 - mu) * inv * w[cidx] + b[cidx];
  float r1 = (x1 - mu) * inv * w[cidx + 64] + b[cidx + 64];
  size_t o = (size_t)t * DMODEL;
  out[o + cidx] = r0;
  out[o + cidx + 64] = r1;
  outb[o + cidx] = f2bf(r0);
  outb[o + cidx + 64] = f2bf(r1);
}

// ---------------- swish(G) * ret_n -> bf16 ----------------------------------
__global__ __launch_bounds__(256) void swishmul_kernel(const float* __restrict__ G,
                                                       const float* __restrict__ rn,
                                                       ushort4* __restrict__ Hb) {
  int i = blockIdx.x * 256 + threadIdx.x;
  float4 g = ((const float4*)G)[i];
  float4 r = ((const float4*)rn)[i];
  ushort4 o;
  o.x = f2bf(g.x / (1.f + expf(-g.x)) * r.x);
  o.y = f2bf(g.y / (1.f + expf(-g.y)) * r.y);
  o.z = f2bf(g.z / (1.f + expf(-g.z)) * r.z);
  o.w = f2bf(g.w / (1.f + expf(-g.w)) * r.w);
  Hb[i] = o;
}

extern "C" void kernel_launch(void* const* d_in, const int* in_sizes, int n_in,
                              void* d_out, int out_size, void* d_ws, size_t ws_size,
                              hipStream_t stream) {
  const float* x = (const float*)d_in[0];
  const float* state = (const float*)d_in[1];
  const float* W_qkv = (const float*)d_in[2];
  const float* W_alpha = (const float*)d_in[3];
  const float* b_alpha = (const float*)d_in[4];
  const float* alpha_base = (const float*)d_in[5];
  const float* gn_w = (const float*)d_in[6];
  const float* gn_b = (const float*)d_in[7];
  const float* W_out = (const float*)d_in[8];
  const float* W_gate = (const float*)d_in[9];
  const int* offset = (const int*)d_in[10];

  float* ws = (float*)d_ws;
  // fp32 regions (float offsets):
  float* qkv = ws;                    // [0,12582912) alive gemm1 -> xpos
  float* G   = ws;                    // overlay after qkv dead
  float* P   = ws + 4194304;          // [4194304,6291456) state partials
  float* ret = ws + 25165824;         // [25165824,29360128)
  float* rn  = ws + 29360128;         // [29360128,33554432)
  float* araw = ws + 33554432;
  float* Acum = ws + 33587200;        // end 33619968 fl

  // bf16 overlays (ushort; offsets in float units *2 shorts):
  unsigned short* xb    = (unsigned short*)(ws + 12582912); // dead after gemm qkv
  unsigned short* Wqkvb = (unsigned short*)(ws + 16777216); // spans ..23068672, dead after gemm qkv
  unsigned short* qb    = (unsigned short*)(ws + 12582912); // [12582912,14680064)
  unsigned short* kb    = (unsigned short*)(ws + 14680064); // [14680064,16777216)
  unsigned short* vb    = (unsigned short*)(ws + 16777216); // [16777216,18874368)
  unsigned short* kT_s  = (unsigned short*)(ws + 18874368); // [18874368,20971520)
  unsigned short* vT_b  = (unsigned short*)(ws + 20971520); // [20971520,23068672)
  unsigned short* stT_b = (unsigned short*)(ws + 23068672); // [23068672,23199744)
  // phase 2 overlays (after retention/state_gemm consumed qb/kb/vb/kT_s):
  unsigned short* rnb    = (unsigned short*)(ws + 12582912);
  unsigned short* Wgateb = (unsigned short*)(ws + 14680064);
  unsigned short* Woutb  = (unsigned short*)(ws + 16777216);
  unsigned short* Hb     = (unsigned short*)(ws + 18874368);

  float* out = (float*)d_out;
  float* out_state = out + 4194304;

  dim3 blk(256);
  f2b_kernel<<<dim3(4096), blk, 0, stream>>>((const float4*)x, (ushort4*)xb);
  f2b_kernel<<<dim3(12288), blk, 0, stream>>>((const float4*)W_qkv, (ushort4*)Wqkvb);
  gemm_bf16_nt<<<dim3(48, 16), blk, 0, stream>>>(xb, Wqkvb, qkv, 2048, 6144, 2048);

  alpha_kernel<<<dim3(512), blk, 0, stream>>>(x, W_alpha, b_alpha, alpha_base, araw);
  cumsum_kernel<<<dim3(16), blk, 0, stream>>>(araw, Acum);
  xpos_kernel<<<dim3(8192), blk, 0, stream>>>(qkv, araw, offset, qb, kb, vb);
  transpose_kv_kernel<<<dim3(32, 2, 32), blk, 0, stream>>>(kb, vb, Acum, kT_s, vT_b);
  transpose_state_kernel<<<dim3(2, 2, 16), blk, 0, stream>>>(state, stT_b);

  retention_mfma<<<dim3(16, 32), blk, 0, stream>>>(qb, kb, vT_b, stT_b, Acum, ret);
  state_gemm<<<dim3(8, 16), blk, 0, stream>>>(kT_s, vT_b, P);
  state_combine<<<dim3(1024), blk, 0, stream>>>(P, state, Acum, out_state);
  groupnorm_kernel<<<dim3(8192), blk, 0, stream>>>(ret, gn_w, gn_b, rn, rnb);

  f2b_kernel<<<dim3(4096), blk, 0, stream>>>((const float4*)W_gate, (ushort4*)Wgateb);
  f2b_kernel<<<dim3(4096), blk, 0, stream>>>((const float4*)W_out, (ushort4*)Woutb);
  gemm_bf16_nt<<<dim3(16, 16), blk, 0, stream>>>(rnb, Wgateb, G, 2048, 2048, 2048);
  swishmul_kernel<<<dim3(4096), blk, 0, stream>>>(G, rn, (ushort4*)Hb);
  gemm_bf16_nt<<<dim3(16, 16), blk, 0, stream>>>(Hb, Woutb, out, 2048, 2048, 2048);
}

// Round 5
// 436.026 us; speedup vs baseline: 6.2436x; 1.0313x over previous
//
#include <hip/hip_runtime.h>
#include <cstddef>

#define SQLEN 2048
#define DMODEL 2048
#define NHEADS 16
#define DHEAD 128

typedef __attribute__((ext_vector_type(8))) short bf16x8;
typedef __attribute__((ext_vector_type(4))) float floatx4;

__device__ __forceinline__ unsigned short f2bf(float f) {
  union { float f; unsigned u; } c; c.f = f;
  unsigned u = c.u;
  unsigned r = u + 0x7fffu + ((u >> 16) & 1u);
  return (unsigned short)(r >> 16);
}
__device__ __forceinline__ float bf2f(unsigned short s) {
  union { unsigned u; float f; } c; c.u = ((unsigned)s) << 16;
  return c.f;
}

// ---------------- fp32 -> bf16 convert (vectorized) -------------------------
__global__ __launch_bounds__(256) void f2b_kernel(const float4* __restrict__ in,
                                                  ushort4* __restrict__ out) {
  int i = blockIdx.x * 256 + threadIdx.x;
  float4 v = in[i];
  ushort4 o;
  o.x = f2bf(v.x); o.y = f2bf(v.y); o.z = f2bf(v.z); o.w = f2bf(v.w);
  out[i] = o;
}

// two-array variant (W_gate, W_out in one launch)
__global__ __launch_bounds__(256) void f2b2_kernel(const float4* __restrict__ in0,
                                                   ushort4* __restrict__ out0,
                                                   const float4* __restrict__ in1,
                                                   ushort4* __restrict__ out1,
                                                   int half_blocks) {
  int b = blockIdx.x;
  const float4* in = (b < half_blocks) ? in0 : in1;
  ushort4* out = (b < half_blocks) ? out0 : out1;
  int i = (b < half_blocks ? b : b - half_blocks) * 256 + threadIdx.x;
  float4 v = in[i];
  ushort4 o;
  o.x = f2bf(v.x); o.y = f2bf(v.y); o.z = f2bf(v.z); o.w = f2bf(v.w);
  out[i] = o;
}

// ---------------- bf16 MFMA GEMM: C[M,N] = A[M,K] @ B[N,K]^T ----------------
__global__ __launch_bounds__(256) void gemm_bf16_nt(const unsigned short* __restrict__ A,
                                                    const unsigned short* __restrict__ B,
                                                    float* __restrict__ C,
                                                    int M, int N, int K) {
  __shared__ __align__(16) unsigned short As[128 * 32];
  __shared__ __align__(16) unsigned short Bs[128 * 32];
  int tid = threadIdx.x;
  int wave = tid >> 6;
  int lane = tid & 63;
  int wm = wave >> 1, wn = wave & 1;
  int quad = lane >> 4, m16 = lane & 15;
  int row0 = blockIdx.y * 128, col0 = blockIdx.x * 128;

  floatx4 acc[4][4];
#pragma unroll
  for (int i = 0; i < 4; i++)
#pragma unroll
    for (int j = 0; j < 4; j++) acc[i][j] = (floatx4){0.f, 0.f, 0.f, 0.f};

  int c0 = tid, c1 = tid + 256;
  int r0c = c0 >> 2, q0c = (c0 & 3) * 8;
  int r1c = c1 >> 2, q1c = (c1 & 3) * 8;

  const size_t sK = (size_t)K;
  for (int k0 = 0; k0 < K; k0 += 32) {
    __builtin_amdgcn_global_load_lds(
        (const __attribute__((address_space(1))) unsigned int*)(A + (size_t)(row0 + r0c) * sK + k0 + q0c),
        (__attribute__((address_space(3))) unsigned int*)(As + c0 * 8), 16, 0, 0);
    __builtin_amdgcn_global_load_lds(
        (const __attribute__((address_space(1))) unsigned int*)(A + (size_t)(row0 + r1c) * sK + k0 + q1c),
        (__attribute__((address_space(3))) unsigned int*)(As + c1 * 8), 16, 0, 0);
    __builtin_amdgcn_global_load_lds(
        (const __attribute__((address_space(1))) unsigned int*)(B + (size_t)(col0 + r0c) * sK + k0 + q0c),
        (__attribute__((address_space(3))) unsigned int*)(Bs + c0 * 8), 16, 0, 0);
    __builtin_amdgcn_global_load_lds(
        (const __attribute__((address_space(1))) unsigned int*)(B + (size_t)(col0 + r1c) * sK + k0 + q1c),
        (__attribute__((address_space(3))) unsigned int*)(Bs + c1 * 8), 16, 0, 0);
    __syncthreads();

    bf16x8 af[4], bfr[4];
#pragma unroll
    for (int i = 0; i < 4; i++)
      af[i] = *(const bf16x8*)(As + (wm * 64 + i * 16 + m16) * 32 + quad * 8);
#pragma unroll
    for (int j = 0; j < 4; j++)
      bfr[j] = *(const bf16x8*)(Bs + (wn * 64 + j * 16 + m16) * 32 + quad * 8);
#pragma unroll
    for (int i = 0; i < 4; i++)
#pragma unroll
      for (int j = 0; j < 4; j++)
        acc[i][j] = __builtin_amdgcn_mfma_f32_16x16x32_bf16(af[i], bfr[j], acc[i][j], 0, 0, 0);
    __syncthreads();
  }

#pragma unroll
  for (int i = 0; i < 4; i++) {
#pragma unroll
    for (int j = 0; j < 4; j++) {
      int rr = row0 + wm * 64 + i * 16 + quad * 4;
      int cc = col0 + wn * 64 + j * 16 + m16;
#pragma unroll
      for (int r = 0; r < 4; r++)
        C[(size_t)(rr + r) * N + cc] = acc[i][j][r];
    }
  }
}

// ------- gate GEMM with fused swish*rn epilogue, bf16 output ---------------
__global__ __launch_bounds__(256) void gemm_swish_nt(const unsigned short* __restrict__ A,
                                                     const unsigned short* __restrict__ B,
                                                     const float* __restrict__ rn,
                                                     unsigned short* __restrict__ Hb,
                                                     int M, int N, int K) {
  __shared__ __align__(16) unsigned short As[128 * 32];
  __shared__ __align__(16) unsigned short Bs[128 * 32];
  int tid = threadIdx.x;
  int wave = tid >> 6;
  int lane = tid & 63;
  int wm = wave >> 1, wn = wave & 1;
  int quad = lane >> 4, m16 = lane & 15;
  int row0 = blockIdx.y * 128, col0 = blockIdx.x * 128;

  floatx4 acc[4][4];
#pragma unroll
  for (int i = 0; i < 4; i++)
#pragma unroll
    for (int j = 0; j < 4; j++) acc[i][j] = (floatx4){0.f, 0.f, 0.f, 0.f};

  int c0 = tid, c1 = tid + 256;
  int r0c = c0 >> 2, q0c = (c0 & 3) * 8;
  int r1c = c1 >> 2, q1c = (c1 & 3) * 8;

  const size_t sK = (size_t)K;
  for (int k0 = 0; k0 < K; k0 += 32) {
    __builtin_amdgcn_global_load_lds(
        (const __attribute__((address_space(1))) unsigned int*)(A + (size_t)(row0 + r0c) * sK + k0 + q0c),
        (__attribute__((address_space(3))) unsigned int*)(As + c0 * 8), 16, 0, 0);
    __builtin_amdgcn_global_load_lds(
        (const __attribute__((address_space(1))) unsigned int*)(A + (size_t)(row0 + r1c) * sK + k0 + q1c),
        (__attribute__((address_space(3))) unsigned int*)(As + c1 * 8), 16, 0, 0);
    __builtin_amdgcn_global_load_lds(
        (const __attribute__((address_space(1))) unsigned int*)(B + (size_t)(col0 + r0c) * sK + k0 + q0c),
        (__attribute__((address_space(3))) unsigned int*)(Bs + c0 * 8), 16, 0, 0);
    __builtin_amdgcn_global_load_lds(
        (const __attribute__((address_space(1))) unsigned int*)(B + (size_t)(col0 + r1c) * sK + k0 + q1c),
        (__attribute__((address_space(3))) unsigned int*)(Bs + c1 * 8), 16, 0, 0);
    __syncthreads();

    bf16x8 af[4], bfr[4];
#pragma unroll
    for (int i = 0; i < 4; i++)
      af[i] = *(const bf16x8*)(As + (wm * 64 + i * 16 + m16) * 32 + quad * 8);
#pragma unroll
    for (int j = 0; j < 4; j++)
      bfr[j] = *(const bf16x8*)(Bs + (wn * 64 + j * 16 + m16) * 32 + quad * 8);
#pragma unroll
    for (int i = 0; i < 4; i++)
#pragma unroll
      for (int j = 0; j < 4; j++)
        acc[i][j] = __builtin_amdgcn_mfma_f32_16x16x32_bf16(af[i], bfr[j], acc[i][j], 0, 0, 0);
    __syncthreads();
  }

#pragma unroll
  for (int i = 0; i < 4; i++) {
#pragma unroll
    for (int j = 0; j < 4; j++) {
      int rr = row0 + wm * 64 + i * 16 + quad * 4;
      int cc = col0 + wn * 64 + j * 16 + m16;
#pragma unroll
      for (int r = 0; r < 4; r++) {
        float g = acc[i][j][r];
        float rv = rn[(size_t)(rr + r) * N + cc];
        float hh = g / (1.f + __expf(-g)) * rv;
        Hb[(size_t)(rr + r) * N + cc] = f2bf(hh);
      }
    }
  }
}

// ---------------- alpha: block = 4 t-rows staged in LDS, loop 16 heads ------
__global__ __launch_bounds__(256) void alpha_kernel(const float* __restrict__ x,
                                                    const float* __restrict__ W_alpha,
                                                    const float* __restrict__ b_alpha,
                                                    const float* __restrict__ alpha_base,
                                                    float* __restrict__ a_raw) {
  __shared__ float xs[4][2048];
  int tid = threadIdx.x;
  int t0 = blockIdx.x * 4;
#pragma unroll
  for (int p = 0; p < 8; p++) {
    int idx = tid + p * 256;
    int row = idx >> 9, c4 = idx & 511;
    *(float4*)&xs[row][c4 * 4] = *(const float4*)(x + (size_t)(t0 + row) * DMODEL + c4 * 4);
  }
  __syncthreads();
  int w = tid >> 6, lane = tid & 63;
  int t = t0 + w;
#pragma unroll
  for (int h = 0; h < NHEADS; h++) {
    const float4* wr = (const float4*)(W_alpha + (size_t)h * DMODEL);
    float s = 0.f;
#pragma unroll
    for (int i = lane; i < 512; i += 64) {
      float4 a = *(const float4*)&xs[w][i * 4];
      float4 b = wr[i];
      s += a.x * b.x + a.y * b.y + a.z * b.z + a.w * b.w;
    }
#pragma unroll
    for (int off = 32; off > 0; off >>= 1) s += __shfl_down(s, off);
    if (lane == 0) {
      float sig = 1.f / (1.f + __expf(-(s + b_alpha[h])));
      a_raw[(size_t)h * SQLEN + t] = alpha_base[h] * 8.f * sig;
    }
  }
}

// ---------------- cumsum ----------------------------------------------------
__global__ __launch_bounds__(256) void cumsum_kernel(const float* __restrict__ a_raw,
                                                     float* __restrict__ A) {
  int h = blockIdx.x;
  __shared__ float part[256];
  int tid = threadIdx.x;
  float v[8];
  float s = 0.f;
#pragma unroll
  for (int i = 0; i < 8; i++) {
    v[i] = a_raw[(size_t)h * SQLEN + tid * 8 + i];
    s += v[i];
  }
  part[tid] = s;
  __syncthreads();
  for (int off = 1; off < 256; off <<= 1) {
    float tmp = (tid >= off) ? part[tid - off] : 0.f;
    __syncthreads();
    part[tid] += tmp;
    __syncthreads();
  }
  float run = (tid > 0) ? part[tid - 1] : 0.f;
#pragma unroll
  for (int i = 0; i < 8; i++) {
    run += v[i];
    A[(size_t)h * SQLEN + tid * 8 + i] = run;
  }
}

// ---------------- xPos: emit q,k,v directly as bf16 [h][t][d] ---------------
__global__ __launch_bounds__(256) void xpos_kernel(const float* __restrict__ qkv,
                                                   const float* __restrict__ a_raw,
                                                   const int* __restrict__ offset_p,
                                                   unsigned short* __restrict__ qb,
                                                   unsigned short* __restrict__ kb,
                                                   unsigned short* __restrict__ vb) {
  int idx = blockIdx.x * 256 + threadIdx.x;
  int j = idx & 63;
  int t = (idx >> 6) & 2047;
  int h = idx >> 17;
  float pos = (float)(t + offset_p[0]);
  float freq = exp2f(-(float)j * (13.287712379549449f / 64.f));
  float ang = pos * freq;
  float sn = __sinf(ang), cs = __cosf(ang);
  float zeta = (2.f * (float)j + 51.2f) / 179.2f;
  float lzp = __log2f(zeta) * pos * (1.f / 512.f);
  float sc = exp2f(lzp);
  float sci = exp2f(-lzp);
  const float* row = qkv + (size_t)t * (3 * DMODEL);
  int base = h * DHEAD + j;
  float q1 = row[base], q2 = row[base + 64];
  float k1 = row[DMODEL + base], k2 = row[DMODEL + base + 64];
  float v1 = row[2 * DMODEL + base], v2 = row[2 * DMODEL + base + 64];
  size_t o = ((size_t)h * SQLEN + t) * DHEAD + j;
  qb[o] = f2bf((q1 * cs - q2 * sn) * sc);
  qb[o + 64] = f2bf((q2 * cs + q1 * sn) * sc);
  float km = (1.f - __expf(a_raw[(size_t)h * SQLEN + t])) * sci;
  kb[o] = f2bf((k1 * cs - k2 * sn) * km);
  kb[o + 64] = f2bf((k2 * cs + k1 * sn) * km);
  vb[o] = f2bf(v1);
  vb[o + 64] = f2bf(v2);
}

// ------- transpose kb/vb [h][t][d] -> [h][d][t]; k gets exp(B-A[t]) scale ---
__global__ __launch_bounds__(256) void transpose_kv_kernel(const unsigned short* __restrict__ kb,
                                                           const unsigned short* __restrict__ vb,
                                                           const float* __restrict__ A,
                                                           unsigned short* __restrict__ kT,
                                                           unsigned short* __restrict__ vT) {
  __shared__ __align__(16) unsigned short tile[64][72];
  int h = blockIdx.z >> 1, sel = blockIdx.z & 1;
  int t0 = blockIdx.x * 64, d0 = blockIdx.y * 64;
  int tid = threadIdx.x;
  const unsigned short* src = (sel ? vb : kb) + ((size_t)h * SQLEN + t0) * DHEAD + d0;
  unsigned short* dst = (sel ? vT : kT) + (size_t)h * (DHEAD * SQLEN) + (size_t)d0 * SQLEN + t0;
  float B = A[(size_t)h * SQLEN + SQLEN - 1];
#pragma unroll
  for (int p = 0; p < 2; p++) {
    int c = tid + p * 256;
    int r = c >> 3, off = (c & 7) * 8;
    bf16x8 in = *(const bf16x8*)(src + (size_t)r * DHEAD + off);
    if (!sel) {
      float w = __expf(B - A[(size_t)h * SQLEN + t0 + r]);
      bf16x8 o;
#pragma unroll
      for (int j = 0; j < 8; j++) o[j] = (short)f2bf(bf2f((unsigned short)in[j]) * w);
      *(bf16x8*)&tile[r][off] = o;
    } else {
      *(bf16x8*)&tile[r][off] = in;
    }
  }
  __syncthreads();
#pragma unroll
  for (int p = 0; p < 2; p++) {
    int c = tid + p * 256;
    int dr = c >> 3, toff = (c & 7) * 8;
    bf16x8 o;
#pragma unroll
    for (int j = 0; j < 8; j++) o[j] = (short)tile[toff + j][dr];
    *(bf16x8*)(dst + (size_t)dr * SQLEN + toff) = o;
  }
}

// ---------------- transpose state -> stT bf16 [h][e][d] ---------------------
__global__ __launch_bounds__(256) void transpose_state_kernel(const float* __restrict__ st,
                                                              unsigned short* __restrict__ stT) {
  __shared__ float tile[64][65];
  int h = blockIdx.z, d0 = blockIdx.x * 64, e0 = blockIdx.y * 64;
  int tid = threadIdx.x;
  const float* src = st + (size_t)h * 16384 + (size_t)d0 * DHEAD + e0;
#pragma unroll
  for (int p = 0; p < 4; p++) {
    int idx = tid + p * 256;
    int r = idx >> 4, c = (idx & 15) * 4;
    float4 f = *(const float4*)(src + (size_t)r * DHEAD + c);
    tile[r][c] = f.x; tile[r][c + 1] = f.y; tile[r][c + 2] = f.z; tile[r][c + 3] = f.w;
  }
  __syncthreads();
  unsigned short* dst = stT + (size_t)h * 16384 + (size_t)e0 * DHEAD + d0;
#pragma unroll
  for (int p = 0; p < 2; p++) {
    int idx = tid + p * 256;
    int er = idx >> 3, doff = (idx & 7) * 8;
    bf16x8 o;
#pragma unroll
    for (int j = 0; j < 8; j++) o[j] = (short)f2bf(tile[doff + j][er]);
    *(bf16x8*)(dst + (size_t)er * DHEAD + doff) = o;
  }
}

// ---------------- retention v3: fused group-norm epilogue -------------------
// Direct-register q fragments (no qs LDS). Decay on S regs. GN per (row,head)
// tile = exactly this block's 64x128 output. Writes rn fp32 + rnb bf16.
__global__ __launch_bounds__(256) void retention_mfma(const unsigned short* __restrict__ qb,
                                                      const unsigned short* __restrict__ kb,
                                                      const unsigned short* __restrict__ vT,
                                                      const unsigned short* __restrict__ stT,
                                                      const float* __restrict__ A,
                                                      const float* __restrict__ gn_w,
                                                      const float* __restrict__ gn_b,
                                                      float* __restrict__ rn,
                                                      unsigned short* __restrict__ rnb) {
  __shared__ __align__(16) unsigned short ks[64 * 128];
  __shared__ __align__(16) unsigned short vs[128 * 64];
  __shared__ __align__(16) unsigned short Ss[64 * 72];
  __shared__ float djs[64];
  int h = blockIdx.x;
  int i0 = blockIdx.y * 64;
  int tid = threadIdx.x;
  int wave = tid >> 6, lane = tid & 63, quad = lane >> 4, m16 = lane & 15;
  const float* Ah = A + (size_t)h * SQLEN;
  float c = Ah[i0];
  int rq = wave * 16 + m16;

  // direct q fragment loads (read-once)
  const unsigned short* qh = qb + ((size_t)h * SQLEN + i0 + rq) * DHEAD;
  bf16x8 qf[4];
#pragma unroll
  for (int dc = 0; dc < 4; dc++)
    qf[dc] = *(const bf16x8*)(qh + dc * 32 + quad * 8);
  float ei = __expf(Ah[i0 + rq] - c);

  // groupnorm weights for this lane's columns
  float wg[8], bg[8];
#pragma unroll
  for (int et = 0; et < 8; et++) {
    int col = h * DHEAD + et * 16 + m16;
    wg[et] = gn_w[col];
    bg[et] = gn_b[col];
  }

  floatx4 acc[8];
#pragma unroll
  for (int et = 0; et < 8; et++) acc[et] = (floatx4){0.f, 0.f, 0.f, 0.f};

  // cross term with initial state: exp(Ai) * q @ stT
  if (c > -87.f) {
    const unsigned short* sp = stT + (size_t)h * 16384;
    float ecr[4];
#pragma unroll
    for (int r = 0; r < 4; r++) ecr[r] = __expf(Ah[i0 + wave * 16 + quad * 4 + r]);
#pragma unroll
    for (int et = 0; et < 8; et++) {
#pragma unroll
      for (int dc = 0; dc < 4; dc++) {
        bf16x8 sf = *(const bf16x8*)(sp + (et * 16 + m16) * DHEAD + dc * 32 + quad * 8);
        acc[et] = __builtin_amdgcn_mfma_f32_16x16x32_bf16(qf[dc], sf, acc[et], 0, 0, 0);
      }
#pragma unroll
      for (int r = 0; r < 4; r++) acc[et][r] *= ecr[r];
    }
  }

  for (int j0 = 0; j0 <= i0; j0 += 64) {
    if (c - Ah[j0 + 63] < -87.f) continue;  // whole tile underflows
    __syncthreads();
    const unsigned short* kh = kb + ((size_t)h * SQLEN + j0) * DHEAD;
    const unsigned short* vh = vT + (size_t)h * (DHEAD * SQLEN) + j0;
#pragma unroll
    for (int p = 0; p < 4; p++) {
      int cch = tid + p * 256;
      int r = cch >> 4, kp = (cch & 15) ^ (r & 7);
      __builtin_amdgcn_global_load_lds(
          (const __attribute__((address_space(1))) unsigned int*)(kh + (size_t)r * DHEAD + kp * 8),
          (__attribute__((address_space(3))) unsigned int*)(ks + cch * 8), 16, 0, 0);
      int e = cch >> 3, tp = (cch & 7) ^ (e & 7);
      __builtin_amdgcn_global_load_lds(
          (const __attribute__((address_space(1))) unsigned int*)(vh + (size_t)e * SQLEN + tp * 8),
          (__attribute__((address_space(3))) unsigned int*)(vs + cch * 8), 16, 0, 0);
    }
    if (tid < 64) djs[tid] = __expf(c - Ah[j0 + tid]);
    __syncthreads();

    bool diag = (j0 == i0);
#pragma unroll
    for (int jt = 0; jt < 4; jt++) {
      floatx4 s = (floatx4){0.f, 0.f, 0.f, 0.f};
#pragma unroll
      for (int dc = 0; dc < 4; dc++) {
        int rk = jt * 16 + m16;
        bf16x8 kf = *(const bf16x8*)(ks + rk * 128 + (((dc * 4 + quad) ^ (rk & 7)) * 8));
        s = __builtin_amdgcn_mfma_f32_16x16x32_bf16(kf, qf[dc], s, 0, 0, 0);
      }
      int jb = jt * 16 + quad * 4;
      float4 dj4 = *(const float4*)&djs[jb];
      ushort4 pk;
      pk.x = f2bf((diag && (jb + 0 > rq)) ? 0.f : s[0] * ei * dj4.x);
      pk.y = f2bf((diag && (jb + 1 > rq)) ? 0.f : s[1] * ei * dj4.y);
      pk.z = f2bf((diag && (jb + 2 > rq)) ? 0.f : s[2] * ei * dj4.z);
      pk.w = f2bf((diag && (jb + 3 > rq)) ? 0.f : s[3] * ei * dj4.w);
      *(ushort4*)(Ss + rq * 72 + jb) = pk;
    }

    // PV (wave-local S rows)
    bf16x8 sfr[2];
#pragma unroll
    for (int kc = 0; kc < 2; kc++)
      sfr[kc] = *(const bf16x8*)(Ss + rq * 72 + kc * 32 + quad * 8);
#pragma unroll
    for (int et = 0; et < 8; et++) {
#pragma unroll
      for (int kc = 0; kc < 2; kc++) {
        int e = et * 16 + m16;
        bf16x8 vf = *(const bf16x8*)(vs + e * 64 + (((kc * 4 + quad) ^ (e & 7)) * 8));
        acc[et] = __builtin_amdgcn_mfma_f32_16x16x32_bf16(sfr[kc], vf, acc[et], 0, 0, 0);
      }
    }
  }

  // fused group norm: stats across 16-lane m16 group x 8 et regs, per r
#pragma unroll
  for (int r = 0; r < 4; r++) {
    float s = 0.f, ss = 0.f;
#pragma unroll
    for (int et = 0; et < 8; et++) {
      float v = acc[et][r];
      s += v; ss += v * v;
    }
#pragma unroll
    for (int off = 8; off > 0; off >>= 1) {
      s += __shfl_xor(s, off);
      ss += __shfl_xor(ss, off);
    }
    float mu = s * (1.f / 128.f);
    float var = ss * (1.f / 128.f) - mu * mu;
    float inv = rsqrtf(var + 1e-5f);
    int row = i0 + wave * 16 + quad * 4 + r;
    size_t o = (size_t)row * DMODEL + h * DHEAD;
#pragma unroll
    for (int et = 0; et < 8; et++) {
      float rv = (acc[et][r] - mu) * inv * wg[et] + bg[et];
      rn[o + et * 16 + m16] = rv;
      rnb[o + et * 16 + m16] = f2bf(rv);
    }
  }
}

// -------- new_state GEMM: P[h,chunk] = kT_s[:,krange] @ vT[:,krange]^T ------
__global__ __launch_bounds__(256) void state_gemm(const unsigned short* __restrict__ kT,
                                                  const unsigned short* __restrict__ vT,
                                                  float* __restrict__ P) {
  __shared__ __align__(16) unsigned short As[128 * 32];
  __shared__ __align__(16) unsigned short Bs[128 * 32];
  int chunk = blockIdx.x, h = blockIdx.y;
  int tid = threadIdx.x;
  int wave = tid >> 6, lane = tid & 63;
  int wm = wave >> 1, wn = wave & 1;
  int quad = lane >> 4, m16 = lane & 15;
  const unsigned short* Ab = kT + (size_t)h * (DHEAD * SQLEN);
  const unsigned short* Bb = vT + (size_t)h * (DHEAD * SQLEN);

  floatx4 acc[4][4];
#pragma unroll
  for (int i = 0; i < 4; i++)
#pragma unroll
    for (int j = 0; j < 4; j++) acc[i][j] = (floatx4){0.f, 0.f, 0.f, 0.f};

  int c0 = tid, c1 = tid + 256;
  int r0c = c0 >> 2, q0c = (c0 & 3) * 8;
  int r1c = c1 >> 2, q1c = (c1 & 3) * 8;

  for (int k0 = chunk * 256; k0 < chunk * 256 + 256; k0 += 32) {
    __builtin_amdgcn_global_load_lds(
        (const __attribute__((address_space(1))) unsigned int*)(Ab + (size_t)r0c * SQLEN + k0 + q0c),
        (__attribute__((address_space(3))) unsigned int*)(As + c0 * 8), 16, 0, 0);
    __builtin_amdgcn_global_load_lds(
        (const __attribute__((address_space(1))) unsigned int*)(Ab + (size_t)r1c * SQLEN + k0 + q1c),
        (__attribute__((address_space(3))) unsigned int*)(As + c1 * 8), 16, 0, 0);
    __builtin_amdgcn_global_load_lds(
        (const __attribute__((address_space(1))) unsigned int*)(Bb + (size_t)r0c * SQLEN + k0 + q0c),
        (__attribute__((address_space(3))) unsigned int*)(Bs + c0 * 8), 16, 0, 0);
    __builtin_amdgcn_global_load_lds(
        (const __attribute__((address_space(1))) unsigned int*)(Bb + (size_t)r1c * SQLEN + k0 + q1c),
        (__attribute__((address_space(3))) unsigned int*)(Bs + c1 * 8), 16, 0, 0);
    __syncthreads();

    bf16x8 af[4], bfr[4];
#pragma unroll
    for (int i = 0; i < 4; i++)
      af[i] = *(const bf16x8*)(As + (wm * 64 + i * 16 + m16) * 32 + quad * 8);
#pragma unroll
    for (int j = 0; j < 4; j++)
      bfr[j] = *(const bf16x8*)(Bs + (wn * 64 + j * 16 + m16) * 32 + quad * 8);
#pragma unroll
    for (int i = 0; i < 4; i++)
#pragma unroll
      for (int j = 0; j < 4; j++)
        acc[i][j] = __builtin_amdgcn_mfma_f32_16x16x32_bf16(af[i], bfr[j], acc[i][j], 0, 0, 0);
    __syncthreads();
  }

  float* Pp = P + (size_t)(h * 8 + chunk) * 16384;
#pragma unroll
  for (int i = 0; i < 4; i++)
#pragma unroll
    for (int j = 0; j < 4; j++) {
      int rr = wm * 64 + i * 16 + quad * 4;
      int cc = wn * 64 + j * 16 + m16;
#pragma unroll
      for (int r = 0; r < 4; r++)
        Pp[(size_t)(rr + r) * DHEAD + cc] = acc[i][j][r];
    }
}

__global__ __launch_bounds__(256) void state_combine(const float* __restrict__ P,
                                                     const float* __restrict__ state,
                                                     const float* __restrict__ A,
                                                     float* __restrict__ out_state) {
  int idx = blockIdx.x * 256 + threadIdx.x;
  int h = idx >> 14;
  int de = idx & 16383;
  float B = A[(size_t)h * SQLEN + SQLEN - 1];
  float s = __expf(B) * state[idx];
#pragma unroll
  for (int c = 0; c < 8; c++) s += P[(size_t)(h * 8 + c) * 16384 + de];
  out_state[idx] = s;
}

extern "C" void kernel_launch(void* const* d_in, const int* in_sizes, int n_in,
                              void* d_out, int out_size, void* d_ws, size_t ws_size,
                              hipStream_t stream) {
  const float* x = (const float*)d_in[0];
  const float* state = (const float*)d_in[1];
  const float* W_qkv = (const float*)d_in[2];
  const float* W_alpha = (const float*)d_in[3];
  const float* b_alpha = (const float*)d_in[4];
  const float* alpha_base = (const float*)d_in[5];
  const float* gn_w = (const float*)d_in[6];
  const float* gn_b = (const float*)d_in[7];
  const float* W_out = (const float*)d_in[8];
  const float* W_gate = (const float*)d_in[9];
  const int* offset = (const int*)d_in[10];

  float* ws = (float*)d_ws;
  // fp32 regions (float offsets):
  float* qkv = ws;                    // [0,12582912) alive gemm1 -> xpos
  float* P   = ws + 4194304;          // overlay (qkv dead after xpos)
  float* rn  = ws + 29360128;         // [29360128,33554432)
  float* araw = ws + 33554432;
  float* Acum = ws + 33587200;

  // bf16 overlays (ushort):
  unsigned short* xb    = (unsigned short*)(ws + 12582912); // dead after qkv gemm
  unsigned short* Wqkvb = (unsigned short*)(ws + 16777216); // dead after qkv gemm
  unsigned short* qb    = (unsigned short*)(ws + 12582912);
  unsigned short* kb    = (unsigned short*)(ws + 14680064);
  unsigned short* vb    = (unsigned short*)(ws + 16777216);
  unsigned short* kT_s  = (unsigned short*)(ws + 18874368);
  unsigned short* vT_b  = (unsigned short*)(ws + 20971520);
  unsigned short* stT_b = (unsigned short*)(ws + 23068672);
  unsigned short* rnb   = (unsigned short*)(ws + 25165824); // old ret region (free)
  // phase 2 overlays (safe: written after their underlying readers finish)
  unsigned short* Wgateb = (unsigned short*)(ws + 14680064); // over kb, after retention
  unsigned short* Woutb  = (unsigned short*)(ws + 16777216); // over vb, after transpose
  unsigned short* Hb     = (unsigned short*)(ws + 18874368); // over kT_s, after state_gemm

  float* out = (float*)d_out;
  float* out_state = out + 4194304;

  dim3 blk(256);
  f2b_kernel<<<dim3(4096), blk, 0, stream>>>((const float4*)x, (ushort4*)xb);
  f2b_kernel<<<dim3(12288), blk, 0, stream>>>((const float4*)W_qkv, (ushort4*)Wqkvb);
  gemm_bf16_nt<<<dim3(48, 16), blk, 0, stream>>>(xb, Wqkvb, qkv, 2048, 6144, 2048);

  alpha_kernel<<<dim3(512), blk, 0, stream>>>(x, W_alpha, b_alpha, alpha_base, araw);
  cumsum_kernel<<<dim3(16), blk, 0, stream>>>(araw, Acum);
  xpos_kernel<<<dim3(8192), blk, 0, stream>>>(qkv, araw, offset, qb, kb, vb);
  transpose_kv_kernel<<<dim3(32, 2, 32), blk, 0, stream>>>(kb, vb, Acum, kT_s, vT_b);
  transpose_state_kernel<<<dim3(2, 2, 16), blk, 0, stream>>>(state, stT_b);

  retention_mfma<<<dim3(16, 32), blk, 0, stream>>>(qb, kb, vT_b, stT_b, Acum,
                                                   gn_w, gn_b, rn, rnb);
  state_gemm<<<dim3(8, 16), blk, 0, stream>>>(kT_s, vT_b, P);
  state_combine<<<dim3(1024), blk, 0, stream>>>(P, state, Acum, out_state);

  f2b2_kernel<<<dim3(8192), blk, 0, stream>>>((const float4*)W_gate, (ushort4*)Wgateb,
                                              (const float4*)W_out, (ushort4*)Woutb, 4096);
  gemm_swish_nt<<<dim3(16, 16), blk, 0, stream>>>(rnb, Wgateb, rn, Hb, 2048, 2048, 2048);
  gemm_bf16_nt<<<dim3(16, 16), blk, 0, stream>>>(Hb, Woutb, out, 2048, 2048, 2048);
}